// Round 11
// baseline (407.950 us; speedup 1.0000x reference)
//
#include <hip/hip_runtime.h>
#include <math.h>

#define NN 50000
#define EE 800000
#define DIN 300
#define DH 128
#define NG 128
#define RSIZE 6250  // NN/8 dst-range per XCD partition

typedef __attribute__((ext_vector_type(8))) short short8;
typedef __attribute__((ext_vector_type(4))) float floatx4;

__device__ __forceinline__ float gelu_exact(float x) {
  return 0.5f * x * (1.0f + erff(x * 0.7071067811865476f));
}

__device__ __forceinline__ void split_bf16(float v, unsigned short& hi, unsigned short& lo) {
  unsigned int u = __float_as_uint(v);
  hi = (unsigned short)(u >> 16);
  float fh = __uint_as_float((unsigned int)hi << 16);
  lo = (unsigned short)(__float_as_uint(v - fh) >> 16);
}

__device__ __forceinline__ unsigned short f2bf_rne(float x) {
  unsigned int u = __float_as_uint(x);
  unsigned int r = (u + 0x7FFFu + ((u >> 16) & 1u)) >> 16;
  return (unsigned short)r;
}

__device__ __forceinline__ float bf_lo(unsigned u) { return __uint_as_float(u << 16); }
__device__ __forceinline__ float bf_hi(unsigned u) { return __uint_as_float(u & 0xFFFF0000u); }

// ---------------- CSR build (XCD-partitioned by dst range) ----------------

__global__ __launch_bounds__(256) void count_part_kernel(const int* __restrict__ ei,
                                                         int* __restrict__ deg,
                                                         int blocksPerRange) {
  const int r = blockIdx.x & 7;
  const int t = blockIdx.x >> 3;
  const int lo = r * RSIZE, hi = lo + RSIZE;
  const int total = EE + NN;
  const int step = blocksPerRange * 256;
  for (int e0 = t * 256; e0 < total; e0 += step) {
    int e = e0 + threadIdx.x;
    if (e < total) {
      int d = (e < EE) ? ei[EE + e] : (e - EE);
      if (d >= lo && d < hi) atomicAdd(&deg[d], 1);
    }
  }
}

__global__ __launch_bounds__(1024) void scan_part_kernel(const int* __restrict__ deg,
                                                         int* __restrict__ rowptr,
                                                         int* __restrict__ bsum) {
  __shared__ int wsum[16];
  const int tid = threadIdx.x;
  const int lane = tid & 63;
  const int wid = tid >> 6;
  int idx = blockIdx.x * 1024 + tid;
  int v = (idx < NN) ? deg[idx] : 0;
  int x = v;
#pragma unroll
  for (int d = 1; d < 64; d <<= 1) {
    int y = __shfl_up(x, d, 64);
    if (lane >= d) x += y;
  }
  if (lane == 63) wsum[wid] = x;
  __syncthreads();
  if (wid == 0) {
    int s = (lane < 16) ? wsum[lane] : 0;
#pragma unroll
    for (int d = 1; d < 16; d <<= 1) {
      int y = __shfl_up(s, d, 64);
      if (lane >= d) s += y;
    }
    if (lane < 16) wsum[lane] = s;
  }
  __syncthreads();
  int woff = (wid > 0) ? wsum[wid - 1] : 0;
  int incl = x + woff;
  if (idx < NN) rowptr[idx] = incl - v;
  if (tid == 1023) bsum[blockIdx.x] = incl;
}

__global__ __launch_bounds__(64) void scan_sums_kernel(const int* __restrict__ bsum,
                                                       int* __restrict__ boff, int nb) {
  int lane = threadIdx.x;
  int v = (lane < nb) ? bsum[lane] : 0;
  int x = v;
#pragma unroll
  for (int d = 1; d < 64; d <<= 1) {
    int y = __shfl_up(x, d, 64);
    if (lane >= d) x += y;
  }
  if (lane < nb) boff[lane] = x - v;
  if (lane == nb - 1) boff[nb] = x;
}

__global__ __launch_bounds__(256) void scan_add_kernel(int* __restrict__ rowptr,
                                                       const int* __restrict__ boff,
                                                       int* __restrict__ cursor, int nb) {
  int i = blockIdx.x * 256 + threadIdx.x;
  if (i < NN) {
    int r = rowptr[i] + boff[i >> 10];
    rowptr[i] = r;
    cursor[i] = r;
  } else if (i == NN) {
    rowptr[NN] = boff[nb];
  }
}

__global__ __launch_bounds__(256) void scatter_part_kernel(const int* __restrict__ ei,
                                                           int* __restrict__ cursor,
                                                           int* __restrict__ colA,
                                                           int blocksPerRange) {
  const int r = blockIdx.x & 7;
  const int t = blockIdx.x >> 3;
  const int lo = r * RSIZE, hi = lo + RSIZE;
  const int total = EE + NN;
  const int step = blocksPerRange * 256;
  for (int e0 = t * 256; e0 < total; e0 += step) {
    int e = e0 + threadIdx.x;
    if (e < total) {
      int d = (e < EE) ? ei[EE + e] : (e - EE);
      if (d >= lo && d < hi) {
        int s = (e < EE) ? ei[e] : d;
        int p = atomicAdd(&cursor[d], 1);
        colA[p] = s;
      }
    }
  }
}

// ---------------- B pre-transpose + split to bf16 hi/lo ----------------

__global__ __launch_bounds__(256) void convert_bt_kernel(const float* __restrict__ B,
                                                         unsigned short* __restrict__ Bth,
                                                         unsigned short* __restrict__ Btl,
                                                         int K, int Kpad) {
  int i = blockIdx.x * 256 + threadIdx.x;
  int n = i / Kpad, k = i % Kpad;
  if (n >= 128) return;
  float v = (k < K) ? B[(long)k * 128 + n] : 0.f;
  unsigned short h, l;
  split_bf16(v, h, l);
  Bth[(long)n * Kpad + k] = h;
  Btl[(long)n * Kpad + k] = l;
}

// ---------------- MFMA split-bf16 GEMM + fused attention row-dots ----------------
// C (bf16) [M,128] = A[M,K] @ B[K,128].
// ZERO LDS, ZERO BARRIERS: each wave owns an independent 16-row strip x 128 cols.
//   - A fragment: global->reg (2 float4/lane), split to hi/lo bf16 in-register,
//     prefetched one K-step ahead (no barrier => prefetch actually survives;
//     the old design's __syncthreads emitted s_waitcnt vmcnt(0) which drained it).
//   - B fragments: global->reg straight from pre-split Bt[n][k] (L1/L2-hot:
//     per-CU per-step B slice is 16KB). All 16 frags issued up front per step
//     => ~18 loads in flight/wave; compiler emits fine-grained vmcnt(N).
//   - Wave covers full 128-col rows => complete row-dots, plain stores.

__global__ __launch_bounds__(256) void gemm_mfma_kernel(
    const float* __restrict__ A,
    const unsigned short* __restrict__ Bth, const unsigned short* __restrict__ Btl,
    unsigned short* __restrict__ C, int M, int K, int Kpad,
    const float* __restrict__ avs, const float* __restrict__ avd,
    float* __restrict__ aS, float* __restrict__ aD) {
  const int lane = threadIdx.x & 63;
  const int w = threadIdx.x >> 6;
  const int q = lane >> 4;
  const int m16 = lane & 15;
  const int row0 = blockIdx.x * 64 + w * 16;  // wave's 16-row strip
  const int myrow = row0 + m16;
  const bool rok = myrow < M;
  const long abase = (long)myrow * K;
  const long bbase = (long)m16 * Kpad + q * 8;  // + ct*16*Kpad + s*32

  floatx4 acc[8];
#pragma unroll
  for (int i = 0; i < 8; i++) acc[i] = (floatx4)(0.f);

  const int nsteps = Kpad / 32;

  float4 vA0, vA1, nA0, nA1;
  auto loadA = [&](int s, float4& x0, float4& x1) {
    const int k0 = s * 32 + q * 8;
    x0 = make_float4(0.f, 0.f, 0.f, 0.f);
    x1 = x0;
    if (rok) {
      if (k0 + 4 <= K) x0 = *(const float4*)&A[abase + k0];
      if (k0 + 8 <= K) x1 = *(const float4*)&A[abase + k0 + 4];
    }
  };

  loadA(0, vA0, vA1);

  for (int s = 0; s < nsteps; s++) {
    // issue ALL B fragment loads for this step (16 x 16B, independent)
    short8 bfh[8], bfl[8];
    const long bofs = bbase + s * 32;
#pragma unroll
    for (int ct = 0; ct < 8; ct++) {
      bfh[ct] = *(const short8*)&Bth[bofs + (long)ct * 16 * Kpad];
      bfl[ct] = *(const short8*)&Btl[bofs + (long)ct * 16 * Kpad];
    }
    // prefetch next A (in flight across this step's MFMAs)
    if (s + 1 < nsteps) loadA(s + 1, nA0, nA1);
    // split current A to hi/lo bf16
    float av[8] = {vA0.x, vA0.y, vA0.z, vA0.w, vA1.x, vA1.y, vA1.z, vA1.w};
    union {
      unsigned u[4];
      short8 s8;
    } Uh, Ul;
#pragma unroll
    for (int i = 0; i < 4; i++) {
      unsigned short ha, la, hb, lb;
      split_bf16(av[2 * i], ha, la);
      split_bf16(av[2 * i + 1], hb, lb);
      Uh.u[i] = (unsigned)ha | ((unsigned)hb << 16);
      Ul.u[i] = (unsigned)la | ((unsigned)lb << 16);
    }
    short8 afh = Uh.s8, afl = Ul.s8;
#pragma unroll
    for (int ct = 0; ct < 8; ct++) {
      acc[ct] = __builtin_amdgcn_mfma_f32_16x16x32_bf16(afh, bfh[ct], acc[ct], 0, 0, 0);
      acc[ct] = __builtin_amdgcn_mfma_f32_16x16x32_bf16(afh, bfl[ct], acc[ct], 0, 0, 0);
      acc[ct] = __builtin_amdgcn_mfma_f32_16x16x32_bf16(afl, bfh[ct], acc[ct], 0, 0, 0);
    }
    vA0 = nA0;
    vA1 = nA1;
  }

  // epilogue: C store + complete row-dots (plain stores, no atomics)
  float avs_r[8], avd_r[8];
#pragma unroll
  for (int ct = 0; ct < 8; ct++) {
    avs_r[ct] = avs[ct * 16 + m16];
    avd_r[ct] = avd[ct * 16 + m16];
  }
#pragma unroll
  for (int reg = 0; reg < 4; reg++) {
    int grow = row0 + q * 4 + reg;
    bool ok = grow < M;
    float ps = 0.f, pd = 0.f;
#pragma unroll
    for (int ct = 0; ct < 8; ct++) {
      float c = acc[ct][reg];
      if (ok) C[(long)grow * 128 + ct * 16 + m16] = f2bf_rne(c);
      ps = fmaf(c, avs_r[ct], ps);
      pd = fmaf(c, avd_r[ct], pd);
    }
#pragma unroll
    for (int d = 1; d < 16; d <<= 1) {
      ps += __shfl_xor(ps, d, 64);
      pd += __shfl_xor(pd, d, 64);
    }
    if (m16 == 0 && ok) {
      aS[grow] = ps;
      aD[grow] = pd;
    }
  }
}

// ---------------- softmax attention + aggregation: one WAVE per dst ----------------
// Half-wave owns one edge (32 lanes x uint2 = 256B row); 4-deep unroll =>
// 8 edges / 4 independent gathers in flight per lane.

__global__ __launch_bounds__(256) void aggregate_kernel(const int* __restrict__ rowptr,
                                                        const int* __restrict__ colA,
                                                        const float* __restrict__ aS,
                                                        const float* __restrict__ aD,
                                                        const unsigned short* __restrict__ Hb,
                                                        const float* __restrict__ bias,
                                                        float* __restrict__ out,
                                                        int apply_gelu) {
  const int lane = threadIdx.x & 63;
  const int dst = blockIdx.x * 4 + (threadIdx.x >> 6);
  if (dst >= NN) return;
  const int start = rowptr[dst];
  const int end = rowptr[dst + 1];
  const int deg = end - start;
  const float ad = aD[dst];
  const int half = lane >> 5;
  const int fl = lane & 31;

  float a0 = 0.f, a1 = 0.f, a2 = 0.f, a3 = 0.f;

  if (deg <= 64) {
    int src = 0;
    float e = -__builtin_inff();
    if (lane < deg) {
      src = colA[start + lane];
      float v = aS[src] + ad;
      e = (v > 0.f) ? v : 0.2f * v;
    }
    float mx = e;
#pragma unroll
    for (int d = 1; d < 64; d <<= 1) mx = fmaxf(mx, __shfl_xor(mx, d, 64));
    float ew = (lane < deg) ? expf(e - mx) : 0.f;
    float ss = ew;
#pragma unroll
    for (int d = 1; d < 64; d <<= 1) ss += __shfl_xor(ss, d, 64);
    float wgt = ew * (1.f / ss);
    for (int j = 0; j < deg; j += 8) {
      int sj[4];
      float wj[4];
#pragma unroll
      for (int i = 0; i < 4; i++) {
        int idx = j + 2 * i + half;
        sj[i] = __shfl(src, idx & 63, 64);
        float ww = __shfl(wgt, idx & 63, 64);
        wj[i] = (idx < deg) ? ww : 0.f;
      }
      uint2 u[4];
#pragma unroll
      for (int i = 0; i < 4; i++) u[i] = *(const uint2*)&Hb[(long)sj[i] * DH + fl * 4];
#pragma unroll
      for (int i = 0; i < 4; i++) {
        a0 = fmaf(wj[i], bf_lo(u[i].x), a0);
        a1 = fmaf(wj[i], bf_hi(u[i].x), a1);
        a2 = fmaf(wj[i], bf_lo(u[i].y), a2);
        a3 = fmaf(wj[i], bf_hi(u[i].y), a3);
      }
    }
  } else {
    float m = -__builtin_inff(), ssum = 0.f;
    for (int c0 = start; c0 < end; c0 += 64) {
      int i = c0 + lane;
      float e = -__builtin_inff();
      if (i < end) {
        int s = colA[i];
        float v = aS[s] + ad;
        e = (v > 0.f) ? v : 0.2f * v;
      }
      float cm = e;
#pragma unroll
      for (int d = 1; d < 64; d <<= 1) cm = fmaxf(cm, __shfl_xor(cm, d, 64));
      float ce = (i < end) ? expf(e - cm) : 0.f;
      float cs = ce;
#pragma unroll
      for (int d = 1; d < 64; d <<= 1) cs += __shfl_xor(cs, d, 64);
      float nm = fmaxf(m, cm);
      ssum = ssum * expf(m - nm) + cs * expf(cm - nm);
      m = nm;
    }
    float inv = 1.f / ssum;
    for (int c0 = start; c0 < end; c0 += 64) {
      int i = c0 + lane;
      int src = 0;
      float wgt = 0.f;
      if (i < end) {
        src = colA[i];
        float v = aS[src] + ad;
        float e = (v > 0.f) ? v : 0.2f * v;
        wgt = expf(e - m) * inv;
      }
      int lim = min(64, end - c0);
      for (int j = 0; j < lim; j += 4) {
        int j0 = j + half;
        int j1 = j + 2 + half;
        int sj0 = __shfl(src, j0 & 63, 64);
        float wj0 = __shfl(wgt, j0 & 63, 64);
        if (j0 >= lim) wj0 = 0.f;
        int sj1 = __shfl(src, j1 & 63, 64);
        float wj1 = __shfl(wgt, j1 & 63, 64);
        if (j1 >= lim) wj1 = 0.f;
        uint2 u0 = *(const uint2*)&Hb[(long)sj0 * DH + fl * 4];
        uint2 u1 = *(const uint2*)&Hb[(long)sj1 * DH + fl * 4];
        a0 = fmaf(wj0, bf_lo(u0.x), a0);
        a1 = fmaf(wj0, bf_hi(u0.x), a1);
        a2 = fmaf(wj0, bf_lo(u0.y), a2);
        a3 = fmaf(wj0, bf_hi(u0.y), a3);
        a0 = fmaf(wj1, bf_lo(u1.x), a0);
        a1 = fmaf(wj1, bf_hi(u1.x), a1);
        a2 = fmaf(wj1, bf_lo(u1.y), a2);
        a3 = fmaf(wj1, bf_hi(u1.y), a3);
      }
    }
  }

  a0 += __shfl_xor(a0, 32, 64);
  a1 += __shfl_xor(a1, 32, 64);
  a2 += __shfl_xor(a2, 32, 64);
  a3 += __shfl_xor(a3, 32, 64);

  if (half == 0) {
    float4 b = *(const float4*)&bias[fl * 4];
    float r0 = a0 + b.x;
    float r1 = a1 + b.y;
    float r2 = a2 + b.z;
    float r3 = a3 + b.w;
    if (apply_gelu) {
      r0 = gelu_exact(r0); r1 = gelu_exact(r1);
      r2 = gelu_exact(r2); r3 = gelu_exact(r3);
    }
    *(float4*)&out[(long)dst * DH + fl * 4] = make_float4(r0, r1, r2, r3);
  }
}

// ---------------- masked per-graph mean pooling (batch is sorted) ----------------

__global__ __launch_bounds__(128) void pool_kernel(const float* __restrict__ H,
                                                   const int* __restrict__ batch,
                                                   const int* __restrict__ pos,
                                                   float* __restrict__ sums,
                                                   float* __restrict__ cnt) {
  const int CH = 64;
  int n0 = blockIdx.x * CH;
  int n1 = min(n0 + CH, NN);
  int f = threadIdx.x;
  float acc = 0.f, c = 0.f;
  int g = batch[n0];
  for (int n = n0; n < n1; n++) {
    int gn = batch[n];
    if (gn != g) {
      atomicAdd(&sums[g * DH + f], acc);
      if (f == 0) atomicAdd(&cnt[g], c);
      acc = 0.f; c = 0.f; g = gn;
    }
    if (pos[n]) {
      acc += H[(long)n * DH + f];
      c += 1.f;
    }
  }
  atomicAdd(&sums[g * DH + f], acc);
  if (f == 0) atomicAdd(&cnt[g], c);
}

// ---------------- head ----------------

__global__ __launch_bounds__(128) void head_kernel(const float* __restrict__ sums,
                                                   const float* __restrict__ cnt,
                                                   const float* __restrict__ Wfc,
                                                   const float* __restrict__ bfc,
                                                   float* __restrict__ out) {
  int g = blockIdx.x;
  int f = threadIdx.x;
  float c = fmaxf(cnt[g], 1.f);
  float logit = sums[g * DH + f] / c;
  out[NG + g * DH + f] = logit;
  float gl = gelu_exact(logit) * Wfc[f];
  __shared__ float red[2];
#pragma unroll
  for (int d = 1; d < 64; d <<= 1) gl += __shfl_xor(gl, d, 64);
  int lane = f & 63, w = f >> 6;
  if (lane == 0) red[w] = gl;
  __syncthreads();
  if (f == 0) out[g] = red[0] + red[1] + bfc[0];
}

// ---------------- launch ----------------

extern "C" void kernel_launch(void* const* d_in, const int* in_sizes, int n_in,
                              void* d_out, int out_size, void* d_ws, size_t ws_size,
                              hipStream_t stream) {
  const float* x   = (const float*)d_in[0];
  const int* ei    = (const int*)d_in[1];
  const int* batch = (const int*)d_in[2];
  const int* pos   = (const int*)d_in[3];
  const float* W1  = (const float*)d_in[5];
  const float* as1 = (const float*)d_in[6];
  const float* ad1 = (const float*)d_in[7];
  const float* b1  = (const float*)d_in[8];
  const float* W2  = (const float*)d_in[9];
  const float* as2 = (const float*)d_in[10];
  const float* ad2 = (const float*)d_in[11];
  const float* b2  = (const float*)d_in[12];
  const float* Wfc = (const float*)d_in[13];
  const float* bfc = (const float*)d_in[14];
  float* out = (float*)d_out;

  const int KP1 = 320;
  const int KP2 = 128;
  const int NB_SCAN = (NN + 1023) / 1024;  // 49
  const int BPR = 416;                      // blocks per dst-range (x8 ranges)

  char* ws = (char*)d_ws;
  size_t off = 0;
  auto nxt = [&](size_t b) -> void* {
    size_t p = off;
    off += (b + 255) & ~(size_t)255;
    return (void*)(ws + p);
  };
  int* rowptr = (int*)nxt((NN + 1) * sizeof(int));
  int* cursor = (int*)nxt(NN * sizeof(int));
  int* colA   = (int*)nxt((size_t)(EE + NN) * sizeof(int));
  int* bsum   = (int*)nxt((NB_SCAN + 1) * sizeof(int));
  int* boff   = (int*)nxt((NB_SCAN + 1) * sizeof(int));
  float* aS   = (float*)nxt((size_t)2 * NN * sizeof(float));
  float* aD   = aS + NN;
  unsigned short* bufAb = (unsigned short*)nxt((size_t)NN * DH * sizeof(short));
  float* bufB = (float*)nxt((size_t)NN * DH * sizeof(float));
  float* sums = (float*)nxt((size_t)(NG * DH + NG) * sizeof(float));
  float* cnt  = sums + NG * DH;
  unsigned short* Bt1h = (unsigned short*)nxt((size_t)128 * KP1 * sizeof(short));
  unsigned short* Bt1l = (unsigned short*)nxt((size_t)128 * KP1 * sizeof(short));
  unsigned short* Bt2h = (unsigned short*)nxt((size_t)128 * KP2 * sizeof(short));
  unsigned short* Bt2l = (unsigned short*)nxt((size_t)128 * KP2 * sizeof(short));

  hipMemsetAsync(cursor, 0, NN * sizeof(int), stream);
  hipMemsetAsync(sums, 0, (NG * DH + NG) * sizeof(float), stream);

  convert_bt_kernel<<<(128 * KP1 + 255) / 256, 256, 0, stream>>>(W1, Bt1h, Bt1l, DIN, KP1);
  convert_bt_kernel<<<(128 * KP2 + 255) / 256, 256, 0, stream>>>(W2, Bt2h, Bt2l, DH, KP2);

  count_part_kernel<<<8 * BPR, 256, 0, stream>>>(ei, cursor, BPR);
  scan_part_kernel<<<NB_SCAN, 1024, 0, stream>>>(cursor, rowptr, bsum);
  scan_sums_kernel<<<1, 64, 0, stream>>>(bsum, boff, NB_SCAN);
  scan_add_kernel<<<(NN + 1 + 255) / 256, 256, 0, stream>>>(rowptr, boff, cursor, NB_SCAN);
  scatter_part_kernel<<<8 * BPR, 256, 0, stream>>>(ei, cursor, colA, BPR);

  const int gblocks = (NN + 63) / 64;
  // layer 1
  gemm_mfma_kernel<<<gblocks, 256, 0, stream>>>(x, Bt1h, Bt1l, bufAb, NN, DIN, KP1,
                                                as1, ad1, aS, aD);
  aggregate_kernel<<<(NN + 3) / 4, 256, 0, stream>>>(rowptr, colA, aS, aD, bufAb, b1, bufB, 1);
  // layer 2
  gemm_mfma_kernel<<<gblocks, 256, 0, stream>>>(bufB, Bt2h, Bt2l, bufAb, NN, DH, KP2,
                                                as2, ad2, aS, aD);
  aggregate_kernel<<<(NN + 3) / 4, 256, 0, stream>>>(rowptr, colA, aS, aD, bufAb, b2, bufB, 0);
  // pooling + head
  pool_kernel<<<(NN + 63) / 64, 128, 0, stream>>>(bufB, batch, pos, sums, cnt);
  head_kernel<<<NG, 128, 0, stream>>>(sums, cnt, Wfc, bfc, out);
}

// Round 12
// 354.953 us; speedup vs baseline: 1.1493x; 1.1493x over previous
//
#include <hip/hip_runtime.h>
#include <math.h>

#define NN 50000
#define EE 800000
#define DIN 300
#define DH 128
#define NG 128
#define RSIZE 6250  // NN/8 dst-range per XCD partition

typedef __attribute__((ext_vector_type(8))) short short8;
typedef __attribute__((ext_vector_type(4))) float floatx4;

__device__ __forceinline__ float gelu_exact(float x) {
  return 0.5f * x * (1.0f + erff(x * 0.7071067811865476f));
}

__device__ __forceinline__ void split_bf16(float v, unsigned short& hi, unsigned short& lo) {
  unsigned int u = __float_as_uint(v);
  hi = (unsigned short)(u >> 16);
  float fh = __uint_as_float((unsigned int)hi << 16);
  lo = (unsigned short)(__float_as_uint(v - fh) >> 16);
}

__device__ __forceinline__ unsigned short f2bf_rne(float x) {
  unsigned int u = __float_as_uint(x);
  unsigned int r = (u + 0x7FFFu + ((u >> 16) & 1u)) >> 16;
  return (unsigned short)r;
}

__device__ __forceinline__ float bf_lo(unsigned u) { return __uint_as_float(u << 16); }
__device__ __forceinline__ float bf_hi(unsigned u) { return __uint_as_float(u & 0xFFFF0000u); }

// async 16B global->LDS DMA (gfx950). LDS dest = wave-uniform base + lane*16.
__device__ __forceinline__ void async_ld16(void* lds, const void* g) {
  __builtin_amdgcn_global_load_lds(
      (const __attribute__((address_space(1))) unsigned int*)(unsigned long long)g,
      (__attribute__((address_space(3))) unsigned int*)(unsigned int)(unsigned long long)lds,
      16, 0, 0);
}

// ---------------- CSR build (XCD-partitioned by dst range) ----------------

__global__ __launch_bounds__(256) void count_part_kernel(const int* __restrict__ ei,
                                                         int* __restrict__ deg,
                                                         int blocksPerRange) {
  const int r = blockIdx.x & 7;
  const int t = blockIdx.x >> 3;
  const int lo = r * RSIZE, hi = lo + RSIZE;
  const int total = EE + NN;
  const int step = blocksPerRange * 256;
  for (int e0 = t * 256; e0 < total; e0 += step) {
    int e = e0 + threadIdx.x;
    if (e < total) {
      int d = (e < EE) ? ei[EE + e] : (e - EE);
      if (d >= lo && d < hi) atomicAdd(&deg[d], 1);
    }
  }
}

__global__ __launch_bounds__(1024) void scan_part_kernel(const int* __restrict__ deg,
                                                         int* __restrict__ rowptr,
                                                         int* __restrict__ bsum) {
  __shared__ int wsum[16];
  const int tid = threadIdx.x;
  const int lane = tid & 63;
  const int wid = tid >> 6;
  int idx = blockIdx.x * 1024 + tid;
  int v = (idx < NN) ? deg[idx] : 0;
  int x = v;
#pragma unroll
  for (int d = 1; d < 64; d <<= 1) {
    int y = __shfl_up(x, d, 64);
    if (lane >= d) x += y;
  }
  if (lane == 63) wsum[wid] = x;
  __syncthreads();
  if (wid == 0) {
    int s = (lane < 16) ? wsum[lane] : 0;
#pragma unroll
    for (int d = 1; d < 16; d <<= 1) {
      int y = __shfl_up(s, d, 64);
      if (lane >= d) s += y;
    }
    if (lane < 16) wsum[lane] = s;
  }
  __syncthreads();
  int woff = (wid > 0) ? wsum[wid - 1] : 0;
  int incl = x + woff;
  if (idx < NN) rowptr[idx] = incl - v;
  if (tid == 1023) bsum[blockIdx.x] = incl;
}

__global__ __launch_bounds__(64) void scan_sums_kernel(const int* __restrict__ bsum,
                                                       int* __restrict__ boff, int nb) {
  int lane = threadIdx.x;
  int v = (lane < nb) ? bsum[lane] : 0;
  int x = v;
#pragma unroll
  for (int d = 1; d < 64; d <<= 1) {
    int y = __shfl_up(x, d, 64);
    if (lane >= d) x += y;
  }
  if (lane < nb) boff[lane] = x - v;
  if (lane == nb - 1) boff[nb] = x;
}

__global__ __launch_bounds__(256) void scan_add_kernel(int* __restrict__ rowptr,
                                                       const int* __restrict__ boff,
                                                       int* __restrict__ cursor, int nb) {
  int i = blockIdx.x * 256 + threadIdx.x;
  if (i < NN) {
    int r = rowptr[i] + boff[i >> 10];
    rowptr[i] = r;
    cursor[i] = r;
  } else if (i == NN) {
    rowptr[NN] = boff[nb];
  }
}

__global__ __launch_bounds__(256) void scatter_part_kernel(const int* __restrict__ ei,
                                                           int* __restrict__ cursor,
                                                           int* __restrict__ colA,
                                                           int blocksPerRange) {
  const int r = blockIdx.x & 7;
  const int t = blockIdx.x >> 3;
  const int lo = r * RSIZE, hi = lo + RSIZE;
  const int total = EE + NN;
  const int step = blocksPerRange * 256;
  for (int e0 = t * 256; e0 < total; e0 += step) {
    int e = e0 + threadIdx.x;
    if (e < total) {
      int d = (e < EE) ? ei[EE + e] : (e - EE);
      if (d >= lo && d < hi) {
        int s = (e < EE) ? ei[e] : d;
        int p = atomicAdd(&cursor[d], 1);
        colA[p] = s;
      }
    }
  }
}

// ---------------- B pre-transpose + split to bf16 hi/lo ----------------

__global__ __launch_bounds__(256) void convert_bt_kernel(const float* __restrict__ B,
                                                         unsigned short* __restrict__ Bth,
                                                         unsigned short* __restrict__ Btl,
                                                         int K, int Kpad) {
  int i = blockIdx.x * 256 + threadIdx.x;
  int n = i / Kpad, k = i % Kpad;
  if (n >= 128) return;
  float v = (k < K) ? B[(long)k * 128 + n] : 0.f;
  unsigned short h, l;
  split_bf16(v, h, l);
  Bth[(long)n * Kpad + k] = h;
  Btl[(long)n * Kpad + k] = l;
}

// ---------------- MFMA split-bf16 GEMM + fused attention row-dots ----------------
// C (bf16) [M,128] = A[M,K] @ B[K,128]; BM=64, BN=64, BK=32; grid (ceil(M/64), 2).
// 1564 blocks (~6/CU, 16KB LDS/buf -> LDS allows 10): multiple independent
// barrier-groups per CU so one block's DMA drain overlaps others' MFMAs.
// Wave w owns rows w*16..+15 x the block's 64 cols:
//   - A frags global->reg (2 float4/lane), split in-register (L3-resident x).
//   - B via global_load_lds DMA (pre-split bf16), double-buffered, XOR-swizzled.
//   - one barrier per K-step.
//   - row-dots are per-64-col partials -> atomicAdd (aS/aD memset before launch).

__global__ __launch_bounds__(256) void gemm_mfma_kernel(
    const float* __restrict__ A,
    const unsigned short* __restrict__ Bth, const unsigned short* __restrict__ Btl,
    unsigned short* __restrict__ C, int M, int K, int Kpad,
    const float* __restrict__ avs, const float* __restrict__ avd,
    float* __restrict__ aS, float* __restrict__ aD) {
  __shared__ __align__(16) unsigned short Bls[2][2][64 * 32];  // [buf][plane][n*32+k] 16KB

  const int tid = threadIdx.x;
  const int lane = tid & 63;
  const int w = tid >> 6;
  const int q = lane >> 4;
  const int m16 = lane & 15;
  const int row0 = blockIdx.x * 64 + w * 16;   // wave's 16-row strip
  const int col0 = blockIdx.y * 64;            // block's 64-col half
  const int myrow = row0 + m16;
  const bool rok = myrow < M;
  const long abase = (long)myrow * K;

  // DMA source geometry: one 16-row DMA per plane per wave covers local rows w*16..+15
  const int rl = lane >> 2, qq0 = lane & 3;
  const int nl = w * 16 + rl;                  // local B row 0..63
  const long boff = (long)(col0 + nl) * Kpad + (long)((qq0 ^ ((nl >> 1) & 3)) * 8);

  floatx4 acc[4];
#pragma unroll
  for (int i = 0; i < 4; i++) acc[i] = (floatx4)(0.f);

  const int nsteps = Kpad / 32;

  float4 vA0, vA1, nA0, nA1;
  nA0 = nA1 = make_float4(0.f, 0.f, 0.f, 0.f);

  auto stageB = [&](int s, int nb) {
    const int k0 = s * 32;
    async_ld16(&Bls[nb][0][(w * 16) * 32], Bth + boff + k0);
    async_ld16(&Bls[nb][1][(w * 16) * 32], Btl + boff + k0);
  };
  auto loadA = [&](int s, float4& x0, float4& x1) {
    const int k0 = s * 32 + q * 8;
    x0 = make_float4(0.f, 0.f, 0.f, 0.f);
    x1 = x0;
    if (rok) {
      if (k0 + 4 <= K) x0 = *(const float4*)&A[abase + k0];
      if (k0 + 8 <= K) x1 = *(const float4*)&A[abase + k0 + 4];
    }
  };

  stageB(0, 0);
  loadA(0, vA0, vA1);
  __syncthreads();  // vmcnt drained before barrier -> DMA complete

  for (int s = 0; s < nsteps; s++) {
    const int cur = s & 1;
    if (s + 1 < nsteps) {
      stageB(s + 1, 1 ^ cur);   // async DMA, zero VGPR cost
      loadA(s + 1, nA0, nA1);   // in flight across this step's MFMAs
    }
    float av[8] = {vA0.x, vA0.y, vA0.z, vA0.w, vA1.x, vA1.y, vA1.z, vA1.w};
    union {
      unsigned u[4];
      short8 s8;
    } Uh, Ul;
#pragma unroll
    for (int i = 0; i < 4; i++) {
      unsigned short ha, la, hb, lb;
      split_bf16(av[2 * i], ha, la);
      split_bf16(av[2 * i + 1], hb, lb);
      Uh.u[i] = (unsigned)ha | ((unsigned)hb << 16);
      Ul.u[i] = (unsigned)la | ((unsigned)lb << 16);
    }
    short8 afh = Uh.s8, afl = Ul.s8;
#pragma unroll
    for (int ct = 0; ct < 4; ct++) {
      int n = ct * 16 + m16;  // local col row in LDS
      int qv = (q ^ ((n >> 1) & 3)) * 8;
      short8 bfh = *(const short8*)&Bls[cur][0][n * 32 + qv];
      short8 bfl = *(const short8*)&Bls[cur][1][n * 32 + qv];
      acc[ct] = __builtin_amdgcn_mfma_f32_16x16x32_bf16(afh, bfh, acc[ct], 0, 0, 0);
      acc[ct] = __builtin_amdgcn_mfma_f32_16x16x32_bf16(afh, bfl, acc[ct], 0, 0, 0);
      acc[ct] = __builtin_amdgcn_mfma_f32_16x16x32_bf16(afl, bfh, acc[ct], 0, 0, 0);
    }
    vA0 = nA0;
    vA1 = nA1;
    __syncthreads();  // single barrier: drains next-step DMA (issued pre-compute)
  }

  // epilogue: C store + row-dot partials (this block's 64 cols) via atomics
  float avs_r[4], avd_r[4];
#pragma unroll
  for (int ct = 0; ct < 4; ct++) {
    avs_r[ct] = avs[col0 + ct * 16 + m16];
    avd_r[ct] = avd[col0 + ct * 16 + m16];
  }
#pragma unroll
  for (int reg = 0; reg < 4; reg++) {
    int grow = row0 + q * 4 + reg;
    bool ok = grow < M;
    float ps = 0.f, pd = 0.f;
#pragma unroll
    for (int ct = 0; ct < 4; ct++) {
      float c = acc[ct][reg];
      if (ok) C[(long)grow * 128 + col0 + ct * 16 + m16] = f2bf_rne(c);
      ps = fmaf(c, avs_r[ct], ps);
      pd = fmaf(c, avd_r[ct], pd);
    }
#pragma unroll
    for (int d = 1; d < 16; d <<= 1) {
      ps += __shfl_xor(ps, d, 64);
      pd += __shfl_xor(pd, d, 64);
    }
    if (m16 == 0 && ok) {
      atomicAdd(&aS[grow], ps);
      atomicAdd(&aD[grow], pd);
    }
  }
}

// ---------------- softmax attention + aggregation: one WAVE per dst ----------------
// Half-wave owns one edge (32 lanes x uint2 = 256B row); 4-deep unroll =>
// 8 edges / 4 independent gathers in flight per lane.

__global__ __launch_bounds__(256) void aggregate_kernel(const int* __restrict__ rowptr,
                                                        const int* __restrict__ colA,
                                                        const float* __restrict__ aS,
                                                        const float* __restrict__ aD,
                                                        const unsigned short* __restrict__ Hb,
                                                        const float* __restrict__ bias,
                                                        float* __restrict__ out,
                                                        int apply_gelu) {
  const int lane = threadIdx.x & 63;
  const int dst = blockIdx.x * 4 + (threadIdx.x >> 6);
  if (dst >= NN) return;
  const int start = rowptr[dst];
  const int end = rowptr[dst + 1];
  const int deg = end - start;
  const float ad = aD[dst];
  const int half = lane >> 5;
  const int fl = lane & 31;

  float a0 = 0.f, a1 = 0.f, a2 = 0.f, a3 = 0.f;

  if (deg <= 64) {
    int src = 0;
    float e = -__builtin_inff();
    if (lane < deg) {
      src = colA[start + lane];
      float v = aS[src] + ad;
      e = (v > 0.f) ? v : 0.2f * v;
    }
    float mx = e;
#pragma unroll
    for (int d = 1; d < 64; d <<= 1) mx = fmaxf(mx, __shfl_xor(mx, d, 64));
    float ew = (lane < deg) ? expf(e - mx) : 0.f;
    float ss = ew;
#pragma unroll
    for (int d = 1; d < 64; d <<= 1) ss += __shfl_xor(ss, d, 64);
    float wgt = ew * (1.f / ss);
    for (int j = 0; j < deg; j += 8) {
      int sj[4];
      float wj[4];
#pragma unroll
      for (int i = 0; i < 4; i++) {
        int idx = j + 2 * i + half;
        sj[i] = __shfl(src, idx & 63, 64);
        float ww = __shfl(wgt, idx & 63, 64);
        wj[i] = (idx < deg) ? ww : 0.f;
      }
      uint2 u[4];
#pragma unroll
      for (int i = 0; i < 4; i++) u[i] = *(const uint2*)&Hb[(long)sj[i] * DH + fl * 4];
#pragma unroll
      for (int i = 0; i < 4; i++) {
        a0 = fmaf(wj[i], bf_lo(u[i].x), a0);
        a1 = fmaf(wj[i], bf_hi(u[i].x), a1);
        a2 = fmaf(wj[i], bf_lo(u[i].y), a2);
        a3 = fmaf(wj[i], bf_hi(u[i].y), a3);
      }
    }
  } else {
    float m = -__builtin_inff(), ssum = 0.f;
    for (int c0 = start; c0 < end; c0 += 64) {
      int i = c0 + lane;
      float e = -__builtin_inff();
      if (i < end) {
        int s = colA[i];
        float v = aS[s] + ad;
        e = (v > 0.f) ? v : 0.2f * v;
      }
      float cm = e;
#pragma unroll
      for (int d = 1; d < 64; d <<= 1) cm = fmaxf(cm, __shfl_xor(cm, d, 64));
      float ce = (i < end) ? expf(e - cm) : 0.f;
      float cs = ce;
#pragma unroll
      for (int d = 1; d < 64; d <<= 1) cs += __shfl_xor(cs, d, 64);
      float nm = fmaxf(m, cm);
      ssum = ssum * expf(m - nm) + cs * expf(cm - nm);
      m = nm;
    }
    float inv = 1.f / ssum;
    for (int c0 = start; c0 < end; c0 += 64) {
      int i = c0 + lane;
      int src = 0;
      float wgt = 0.f;
      if (i < end) {
        src = colA[i];
        float v = aS[src] + ad;
        float e = (v > 0.f) ? v : 0.2f * v;
        wgt = expf(e - m) * inv;
      }
      int lim = min(64, end - c0);
      for (int j = 0; j < lim; j += 4) {
        int j0 = j + half;
        int j1 = j + 2 + half;
        int sj0 = __shfl(src, j0 & 63, 64);
        float wj0 = __shfl(wgt, j0 & 63, 64);
        if (j0 >= lim) wj0 = 0.f;
        int sj1 = __shfl(src, j1 & 63, 64);
        float wj1 = __shfl(wgt, j1 & 63, 64);
        if (j1 >= lim) wj1 = 0.f;
        uint2 u0 = *(const uint2*)&Hb[(long)sj0 * DH + fl * 4];
        uint2 u1 = *(const uint2*)&Hb[(long)sj1 * DH + fl * 4];
        a0 = fmaf(wj0, bf_lo(u0.x), a0);
        a1 = fmaf(wj0, bf_hi(u0.x), a1);
        a2 = fmaf(wj0, bf_lo(u0.y), a2);
        a3 = fmaf(wj0, bf_hi(u0.y), a3);
        a0 = fmaf(wj1, bf_lo(u1.x), a0);
        a1 = fmaf(wj1, bf_hi(u1.x), a1);
        a2 = fmaf(wj1, bf_lo(u1.y), a2);
        a3 = fmaf(wj1, bf_hi(u1.y), a3);
      }
    }
  }

  a0 += __shfl_xor(a0, 32, 64);
  a1 += __shfl_xor(a1, 32, 64);
  a2 += __shfl_xor(a2, 32, 64);
  a3 += __shfl_xor(a3, 32, 64);

  if (half == 0) {
    float4 b = *(const float4*)&bias[fl * 4];
    float r0 = a0 + b.x;
    float r1 = a1 + b.y;
    float r2 = a2 + b.z;
    float r3 = a3 + b.w;
    if (apply_gelu) {
      r0 = gelu_exact(r0); r1 = gelu_exact(r1);
      r2 = gelu_exact(r2); r3 = gelu_exact(r3);
    }
    *(float4*)&out[(long)dst * DH + fl * 4] = make_float4(r0, r1, r2, r3);
  }
}

// ---------------- masked per-graph mean pooling (batch is sorted) ----------------

__global__ __launch_bounds__(128) void pool_kernel(const float* __restrict__ H,
                                                   const int* __restrict__ batch,
                                                   const int* __restrict__ pos,
                                                   float* __restrict__ sums,
                                                   float* __restrict__ cnt) {
  const int CH = 64;
  int n0 = blockIdx.x * CH;
  int n1 = min(n0 + CH, NN);
  int f = threadIdx.x;
  float acc = 0.f, c = 0.f;
  int g = batch[n0];
  for (int n = n0; n < n1; n++) {
    int gn = batch[n];
    if (gn != g) {
      atomicAdd(&sums[g * DH + f], acc);
      if (f == 0) atomicAdd(&cnt[g], c);
      acc = 0.f; c = 0.f; g = gn;
    }
    if (pos[n]) {
      acc += H[(long)n * DH + f];
      c += 1.f;
    }
  }
  atomicAdd(&sums[g * DH + f], acc);
  if (f == 0) atomicAdd(&cnt[g], c);
}

// ---------------- head ----------------

__global__ __launch_bounds__(128) void head_kernel(const float* __restrict__ sums,
                                                   const float* __restrict__ cnt,
                                                   const float* __restrict__ Wfc,
                                                   const float* __restrict__ bfc,
                                                   float* __restrict__ out) {
  int g = blockIdx.x;
  int f = threadIdx.x;
  float c = fmaxf(cnt[g], 1.f);
  float logit = sums[g * DH + f] / c;
  out[NG + g * DH + f] = logit;
  float gl = gelu_exact(logit) * Wfc[f];
  __shared__ float red[2];
#pragma unroll
  for (int d = 1; d < 64; d <<= 1) gl += __shfl_xor(gl, d, 64);
  int lane = f & 63, w = f >> 6;
  if (lane == 0) red[w] = gl;
  __syncthreads();
  if (f == 0) out[g] = red[0] + red[1] + bfc[0];
}

// ---------------- launch ----------------

extern "C" void kernel_launch(void* const* d_in, const int* in_sizes, int n_in,
                              void* d_out, int out_size, void* d_ws, size_t ws_size,
                              hipStream_t stream) {
  const float* x   = (const float*)d_in[0];
  const int* ei    = (const int*)d_in[1];
  const int* batch = (const int*)d_in[2];
  const int* pos   = (const int*)d_in[3];
  const float* W1  = (const float*)d_in[5];
  const float* as1 = (const float*)d_in[6];
  const float* ad1 = (const float*)d_in[7];
  const float* b1  = (const float*)d_in[8];
  const float* W2  = (const float*)d_in[9];
  const float* as2 = (const float*)d_in[10];
  const float* ad2 = (const float*)d_in[11];
  const float* b2  = (const float*)d_in[12];
  const float* Wfc = (const float*)d_in[13];
  const float* bfc = (const float*)d_in[14];
  float* out = (float*)d_out;

  const int KP1 = 320;
  const int KP2 = 128;
  const int NB_SCAN = (NN + 1023) / 1024;  // 49
  const int BPR = 416;                      // blocks per dst-range (x8 ranges)

  char* ws = (char*)d_ws;
  size_t off = 0;
  auto nxt = [&](size_t b) -> void* {
    size_t p = off;
    off += (b + 255) & ~(size_t)255;
    return (void*)(ws + p);
  };
  int* rowptr = (int*)nxt((NN + 1) * sizeof(int));
  int* cursor = (int*)nxt(NN * sizeof(int));
  int* colA   = (int*)nxt((size_t)(EE + NN) * sizeof(int));
  int* bsum   = (int*)nxt((NB_SCAN + 1) * sizeof(int));
  int* boff   = (int*)nxt((NB_SCAN + 1) * sizeof(int));
  float* aS   = (float*)nxt((size_t)2 * NN * sizeof(float));
  float* aD   = aS + NN;
  unsigned short* bufAb = (unsigned short*)nxt((size_t)NN * DH * sizeof(short));
  float* bufB = (float*)nxt((size_t)NN * DH * sizeof(float));
  float* sums = (float*)nxt((size_t)(NG * DH + NG) * sizeof(float));
  float* cnt  = sums + NG * DH;
  unsigned short* Bt1h = (unsigned short*)nxt((size_t)128 * KP1 * sizeof(short));
  unsigned short* Bt1l = (unsigned short*)nxt((size_t)128 * KP1 * sizeof(short));
  unsigned short* Bt2h = (unsigned short*)nxt((size_t)128 * KP2 * sizeof(short));
  unsigned short* Bt2l = (unsigned short*)nxt((size_t)128 * KP2 * sizeof(short));

  hipMemsetAsync(cursor, 0, NN * sizeof(int), stream);
  hipMemsetAsync(sums, 0, (NG * DH + NG) * sizeof(float), stream);
  hipMemsetAsync(aS, 0, (size_t)2 * NN * sizeof(float), stream);

  convert_bt_kernel<<<(128 * KP1 + 255) / 256, 256, 0, stream>>>(W1, Bt1h, Bt1l, DIN, KP1);
  convert_bt_kernel<<<(128 * KP2 + 255) / 256, 256, 0, stream>>>(W2, Bt2h, Bt2l, DH, KP2);

  count_part_kernel<<<8 * BPR, 256, 0, stream>>>(ei, cursor, BPR);
  scan_part_kernel<<<NB_SCAN, 1024, 0, stream>>>(cursor, rowptr, bsum);
  scan_sums_kernel<<<1, 64, 0, stream>>>(bsum, boff, NB_SCAN);
  scan_add_kernel<<<(NN + 1 + 255) / 256, 256, 0, stream>>>(rowptr, boff, cursor, NB_SCAN);
  scatter_part_kernel<<<8 * BPR, 256, 0, stream>>>(ei, cursor, colA, BPR);

  const dim3 ggrid((NN + 63) / 64, 2);
  // layer 1
  gemm_mfma_kernel<<<ggrid, 256, 0, stream>>>(x, Bt1h, Bt1l, bufAb, NN, DIN, KP1,
                                              as1, ad1, aS, aD);
  aggregate_kernel<<<(NN + 3) / 4, 256, 0, stream>>>(rowptr, colA, aS, aD, bufAb, b1, bufB, 1);
  // layer 2
  hipMemsetAsync(aS, 0, (size_t)2 * NN * sizeof(float), stream);
  gemm_mfma_kernel<<<ggrid, 256, 0, stream>>>(bufB, Bt2h, Bt2l, bufAb, NN, DH, KP2,
                                              as2, ad2, aS, aD);
  aggregate_kernel<<<(NN + 3) / 4, 256, 0, stream>>>(rowptr, colA, aS, aD, bufAb, b2, bufB, 0);
  // pooling + head
  pool_kernel<<<(NN + 63) / 64, 128, 0, stream>>>(bufB, batch, pos, sums, cnt);
  head_kernel<<<NG, 128, 0, stream>>>(sums, cnt, Wfc, bfc, out);
}

// Round 13
// 340.743 us; speedup vs baseline: 1.1972x; 1.0417x over previous
//
#include <hip/hip_runtime.h>
#include <math.h>

#define NN 50000
#define EE 800000
#define DIN 300
#define DH 128
#define NG 128
#define RSIZE 6250  // NN/8 dst-range per XCD partition

typedef __attribute__((ext_vector_type(8))) short short8;
typedef __attribute__((ext_vector_type(4))) float floatx4;

__device__ __forceinline__ float gelu_exact(float x) {
  return 0.5f * x * (1.0f + erff(x * 0.7071067811865476f));
}

__device__ __forceinline__ void split_bf16(float v, unsigned short& hi, unsigned short& lo) {
  unsigned int u = __float_as_uint(v);
  hi = (unsigned short)(u >> 16);
  float fh = __uint_as_float((unsigned int)hi << 16);
  lo = (unsigned short)(__float_as_uint(v - fh) >> 16);
}

__device__ __forceinline__ unsigned short f2bf_rne(float x) {
  unsigned int u = __float_as_uint(x);
  unsigned int r = (u + 0x7FFFu + ((u >> 16) & 1u)) >> 16;
  return (unsigned short)r;
}

__device__ __forceinline__ float bf_lo(unsigned u) { return __uint_as_float(u << 16); }
__device__ __forceinline__ float bf_hi(unsigned u) { return __uint_as_float(u & 0xFFFF0000u); }

// async 16B global->LDS DMA (gfx950). LDS dest = wave-uniform base + lane*16.
__device__ __forceinline__ void async_ld16(void* lds, const void* g) {
  __builtin_amdgcn_global_load_lds(
      (const __attribute__((address_space(1))) unsigned int*)(unsigned long long)g,
      (__attribute__((address_space(3))) unsigned int*)(unsigned int)(unsigned long long)lds,
      16, 0, 0);
}

// ---------------- CSR build (XCD-partitioned by dst range) ----------------

__global__ __launch_bounds__(256) void count_part_kernel(const int* __restrict__ ei,
                                                         int* __restrict__ deg,
                                                         int blocksPerRange) {
  const int r = blockIdx.x & 7;
  const int t = blockIdx.x >> 3;
  const int lo = r * RSIZE, hi = lo + RSIZE;
  const int total = EE + NN;
  const int step = blocksPerRange * 256;
  for (int e0 = t * 256; e0 < total; e0 += step) {
    int e = e0 + threadIdx.x;
    if (e < total) {
      int d = (e < EE) ? ei[EE + e] : (e - EE);
      if (d >= lo && d < hi) atomicAdd(&deg[d], 1);
    }
  }
}

__global__ __launch_bounds__(1024) void scan_part_kernel(const int* __restrict__ deg,
                                                         int* __restrict__ rowptr,
                                                         int* __restrict__ bsum) {
  __shared__ int wsum[16];
  const int tid = threadIdx.x;
  const int lane = tid & 63;
  const int wid = tid >> 6;
  int idx = blockIdx.x * 1024 + tid;
  int v = (idx < NN) ? deg[idx] : 0;
  int x = v;
#pragma unroll
  for (int d = 1; d < 64; d <<= 1) {
    int y = __shfl_up(x, d, 64);
    if (lane >= d) x += y;
  }
  if (lane == 63) wsum[wid] = x;
  __syncthreads();
  if (wid == 0) {
    int s = (lane < 16) ? wsum[lane] : 0;
#pragma unroll
    for (int d = 1; d < 16; d <<= 1) {
      int y = __shfl_up(s, d, 64);
      if (lane >= d) s += y;
    }
    if (lane < 16) wsum[lane] = s;
  }
  __syncthreads();
  int woff = (wid > 0) ? wsum[wid - 1] : 0;
  int incl = x + woff;
  if (idx < NN) rowptr[idx] = incl - v;
  if (tid == 1023) bsum[blockIdx.x] = incl;
}

__global__ __launch_bounds__(64) void scan_sums_kernel(const int* __restrict__ bsum,
                                                       int* __restrict__ boff, int nb) {
  int lane = threadIdx.x;
  int v = (lane < nb) ? bsum[lane] : 0;
  int x = v;
#pragma unroll
  for (int d = 1; d < 64; d <<= 1) {
    int y = __shfl_up(x, d, 64);
    if (lane >= d) x += y;
  }
  if (lane < nb) boff[lane] = x - v;
  if (lane == nb - 1) boff[nb] = x;
}

__global__ __launch_bounds__(256) void scan_add_kernel(int* __restrict__ rowptr,
                                                       const int* __restrict__ boff,
                                                       int* __restrict__ cursor, int nb) {
  int i = blockIdx.x * 256 + threadIdx.x;
  if (i < NN) {
    int r = rowptr[i] + boff[i >> 10];
    rowptr[i] = r;
    cursor[i] = r;
  } else if (i == NN) {
    rowptr[NN] = boff[nb];
  }
}

__global__ __launch_bounds__(256) void scatter_part_kernel(const int* __restrict__ ei,
                                                           int* __restrict__ cursor,
                                                           int* __restrict__ colA,
                                                           int blocksPerRange) {
  const int r = blockIdx.x & 7;
  const int t = blockIdx.x >> 3;
  const int lo = r * RSIZE, hi = lo + RSIZE;
  const int total = EE + NN;
  const int step = blocksPerRange * 256;
  for (int e0 = t * 256; e0 < total; e0 += step) {
    int e = e0 + threadIdx.x;
    if (e < total) {
      int d = (e < EE) ? ei[EE + e] : (e - EE);
      if (d >= lo && d < hi) {
        int s = (e < EE) ? ei[e] : d;
        int p = atomicAdd(&cursor[d], 1);
        colA[p] = s;
      }
    }
  }
}

// ---------------- B pre-transpose + split to bf16 hi/lo ----------------

__global__ __launch_bounds__(256) void convert_bt_kernel(const float* __restrict__ B,
                                                         unsigned short* __restrict__ Bth,
                                                         unsigned short* __restrict__ Btl,
                                                         int K, int Kpad) {
  int i = blockIdx.x * 256 + threadIdx.x;
  int n = i / Kpad, k = i % Kpad;
  if (n >= 128) return;
  float v = (k < K) ? B[(long)k * 128 + n] : 0.f;
  unsigned short h, l;
  split_bf16(v, h, l);
  Bth[(long)n * Kpad + k] = h;
  Btl[(long)n * Kpad + k] = l;
}

// ---------------- MFMA split-bf16 GEMM + fused attention row-dots ----------------
// Round-9 design (best measured: 43us GEMM1, FETCH 33MB): BM=64, BN=128, BK=32.
// Wave w owns rows w*16..+15 x all 128 cols; A frags global->reg; B via
// double-buffered global_load_lds DMA, XOR-swizzled; one barrier per K-step;
// full-row dots -> plain stores (no atomics, no memsets).

__global__ __launch_bounds__(256) void gemm_mfma_kernel(
    const float* __restrict__ A,
    const unsigned short* __restrict__ Bth, const unsigned short* __restrict__ Btl,
    unsigned short* __restrict__ C, int M, int K, int Kpad,
    const float* __restrict__ avs, const float* __restrict__ avd,
    float* __restrict__ aS, float* __restrict__ aD) {
  __shared__ __align__(16) unsigned short Bls[2][2][128 * 32];  // [buf][plane][n*32+k]

  const int tid = threadIdx.x;
  const int lane = tid & 63;
  const int w = tid >> 6;
  const int q = lane >> 4;
  const int m16 = lane & 15;
  const int row0 = blockIdx.x * 64;
  const int myrow = row0 + w * 16 + m16;
  const bool rok = myrow < M;
  const long abase = (long)myrow * K;

  const int rl = lane >> 2, qq0 = lane & 3;
  const int nb0 = w * 16 + rl;
  const int nb1 = 64 + w * 16 + rl;
  const long boff0 = (long)nb0 * Kpad + (long)((qq0 ^ ((nb0 >> 1) & 3)) * 8);
  const long boff1 = (long)nb1 * Kpad + (long)((qq0 ^ ((nb1 >> 1) & 3)) * 8);

  floatx4 acc[8];
#pragma unroll
  for (int i = 0; i < 8; i++) acc[i] = (floatx4)(0.f);

  const int nsteps = Kpad / 32;

  float4 vA0, vA1, nA0, nA1;
  nA0 = nA1 = make_float4(0.f, 0.f, 0.f, 0.f);

  auto stageB = [&](int s, int nb) {
    const int k0 = s * 32;
    async_ld16(&Bls[nb][0][(w * 16) * 32], Bth + boff0 + k0);
    async_ld16(&Bls[nb][0][(64 + w * 16) * 32], Bth + boff1 + k0);
    async_ld16(&Bls[nb][1][(w * 16) * 32], Btl + boff0 + k0);
    async_ld16(&Bls[nb][1][(64 + w * 16) * 32], Btl + boff1 + k0);
  };
  auto loadA = [&](int s, float4& x0, float4& x1) {
    const int k0 = s * 32 + q * 8;
    x0 = make_float4(0.f, 0.f, 0.f, 0.f);
    x1 = x0;
    if (rok) {
      if (k0 + 4 <= K) x0 = *(const float4*)&A[abase + k0];
      if (k0 + 8 <= K) x1 = *(const float4*)&A[abase + k0 + 4];
    }
  };

  stageB(0, 0);
  loadA(0, vA0, vA1);
  __syncthreads();

  for (int s = 0; s < nsteps; s++) {
    const int cur = s & 1;
    if (s + 1 < nsteps) {
      stageB(s + 1, 1 ^ cur);
      loadA(s + 1, nA0, nA1);
    }
    float av[8] = {vA0.x, vA0.y, vA0.z, vA0.w, vA1.x, vA1.y, vA1.z, vA1.w};
    union {
      unsigned u[4];
      short8 s8;
    } Uh, Ul;
#pragma unroll
    for (int i = 0; i < 4; i++) {
      unsigned short ha, la, hb, lb;
      split_bf16(av[2 * i], ha, la);
      split_bf16(av[2 * i + 1], hb, lb);
      Uh.u[i] = (unsigned)ha | ((unsigned)hb << 16);
      Ul.u[i] = (unsigned)la | ((unsigned)lb << 16);
    }
    short8 afh = Uh.s8, afl = Ul.s8;
#pragma unroll
    for (int ct = 0; ct < 8; ct++) {
      int n = ct * 16 + m16;
      int qv = (q ^ ((n >> 1) & 3)) * 8;
      short8 bfh = *(const short8*)&Bls[cur][0][n * 32 + qv];
      short8 bfl = *(const short8*)&Bls[cur][1][n * 32 + qv];
      acc[ct] = __builtin_amdgcn_mfma_f32_16x16x32_bf16(afh, bfh, acc[ct], 0, 0, 0);
      acc[ct] = __builtin_amdgcn_mfma_f32_16x16x32_bf16(afh, bfl, acc[ct], 0, 0, 0);
      acc[ct] = __builtin_amdgcn_mfma_f32_16x16x32_bf16(afl, bfh, acc[ct], 0, 0, 0);
    }
    vA0 = nA0;
    vA1 = nA1;
    __syncthreads();
  }

  float avs_r[8], avd_r[8];
#pragma unroll
  for (int ct = 0; ct < 8; ct++) {
    avs_r[ct] = avs[ct * 16 + m16];
    avd_r[ct] = avd[ct * 16 + m16];
  }
#pragma unroll
  for (int reg = 0; reg < 4; reg++) {
    int grow = row0 + w * 16 + q * 4 + reg;
    bool ok = grow < M;
    float ps = 0.f, pd = 0.f;
#pragma unroll
    for (int ct = 0; ct < 8; ct++) {
      float c = acc[ct][reg];
      if (ok) C[(long)grow * 128 + ct * 16 + m16] = f2bf_rne(c);
      ps = fmaf(c, avs_r[ct], ps);
      pd = fmaf(c, avd_r[ct], pd);
    }
#pragma unroll
    for (int d = 1; d < 16; d <<= 1) {
      ps += __shfl_xor(ps, d, 64);
      pd += __shfl_xor(pd, d, 64);
    }
    if (m16 == 0 && ok) {
      aS[grow] = ps;
      aD[grow] = pd;
    }
  }
}

// ---------------- softmax attention + aggregation: one WAVE per dst ----------------
// QUARTER-wave owns one edge: 16 lanes x uint4(16B) = 256B row, 4 edges per
// load instruction (1KB/instr, 2x bytes/instr vs uint2), unroll 2 => 8 edges
// in flight per wave. 8 accumulators/lane; combine via shfl_xor(16,32).

__global__ __launch_bounds__(256) void aggregate_kernel(const int* __restrict__ rowptr,
                                                        const int* __restrict__ colA,
                                                        const float* __restrict__ aS,
                                                        const float* __restrict__ aD,
                                                        const unsigned short* __restrict__ Hb,
                                                        const float* __restrict__ bias,
                                                        float* __restrict__ out,
                                                        int apply_gelu) {
  const int lane = threadIdx.x & 63;
  const int dst = blockIdx.x * 4 + (threadIdx.x >> 6);
  if (dst >= NN) return;
  const int start = rowptr[dst];
  const int end = rowptr[dst + 1];
  const int deg = end - start;
  const float ad = aD[dst];
  const int qg = lane >> 4;   // quarter-wave (edge slot)
  const int fl = lane & 15;   // feature octet index: feats fl*8..fl*8+7

  float a0 = 0.f, a1 = 0.f, a2 = 0.f, a3 = 0.f;
  float a4 = 0.f, a5 = 0.f, a6 = 0.f, a7 = 0.f;

  auto gather8 = [&](int sj0, float wj0, int sj1, float wj1) {
    uint4 u0 = *(const uint4*)&Hb[(long)sj0 * DH + fl * 8];
    uint4 u1 = *(const uint4*)&Hb[(long)sj1 * DH + fl * 8];
    a0 = fmaf(wj0, bf_lo(u0.x), a0);
    a1 = fmaf(wj0, bf_hi(u0.x), a1);
    a2 = fmaf(wj0, bf_lo(u0.y), a2);
    a3 = fmaf(wj0, bf_hi(u0.y), a3);
    a4 = fmaf(wj0, bf_lo(u0.z), a4);
    a5 = fmaf(wj0, bf_hi(u0.z), a5);
    a6 = fmaf(wj0, bf_lo(u0.w), a6);
    a7 = fmaf(wj0, bf_hi(u0.w), a7);
    a0 = fmaf(wj1, bf_lo(u1.x), a0);
    a1 = fmaf(wj1, bf_hi(u1.x), a1);
    a2 = fmaf(wj1, bf_lo(u1.y), a2);
    a3 = fmaf(wj1, bf_hi(u1.y), a3);
    a4 = fmaf(wj1, bf_lo(u1.z), a4);
    a5 = fmaf(wj1, bf_hi(u1.z), a5);
    a6 = fmaf(wj1, bf_lo(u1.w), a6);
    a7 = fmaf(wj1, bf_hi(u1.w), a7);
  };

  if (deg <= 64) {
    int src = 0;
    float e = -__builtin_inff();
    if (lane < deg) {
      src = colA[start + lane];
      float v = aS[src] + ad;
      e = (v > 0.f) ? v : 0.2f * v;
    }
    float mx = e;
#pragma unroll
    for (int d = 1; d < 64; d <<= 1) mx = fmaxf(mx, __shfl_xor(mx, d, 64));
    float ew = (lane < deg) ? expf(e - mx) : 0.f;
    float ss = ew;
#pragma unroll
    for (int d = 1; d < 64; d <<= 1) ss += __shfl_xor(ss, d, 64);
    float wgt = ew * (1.f / ss);
    for (int j = 0; j < deg; j += 8) {
      int i0 = j + qg;          // <= 63 (j<=56, qg<=3... j max 56+? deg<=64 -> j<=56; i0<=59)
      int i1 = j + 4 + qg;      // <= 63
      int sj0 = __shfl(src, i0 & 63, 64);
      float wj0 = __shfl(wgt, i0 & 63, 64);
      if (i0 >= deg) wj0 = 0.f;
      int sj1 = __shfl(src, i1 & 63, 64);
      float wj1 = __shfl(wgt, i1 & 63, 64);
      if (i1 >= deg) wj1 = 0.f;
      gather8(sj0, wj0, sj1, wj1);
    }
  } else {
    // generic path (deg > 64, practically never): online softmax, then gather
    float m = -__builtin_inff(), ssum = 0.f;
    for (int c0 = start; c0 < end; c0 += 64) {
      int i = c0 + lane;
      float e = -__builtin_inff();
      if (i < end) {
        int s = colA[i];
        float v = aS[s] + ad;
        e = (v > 0.f) ? v : 0.2f * v;
      }
      float cm = e;
#pragma unroll
      for (int d = 1; d < 64; d <<= 1) cm = fmaxf(cm, __shfl_xor(cm, d, 64));
      float ce = (i < end) ? expf(e - cm) : 0.f;
      float cs = ce;
#pragma unroll
      for (int d = 1; d < 64; d <<= 1) cs += __shfl_xor(cs, d, 64);
      float nm = fmaxf(m, cm);
      ssum = ssum * expf(m - nm) + cs * expf(cm - nm);
      m = nm;
    }
    float inv = 1.f / ssum;
    for (int c0 = start; c0 < end; c0 += 64) {
      int i = c0 + lane;
      int src = 0;
      float wgt = 0.f;
      if (i < end) {
        src = colA[i];
        float v = aS[src] + ad;
        float e = (v > 0.f) ? v : 0.2f * v;
        wgt = expf(e - m) * inv;
      }
      int lim = min(64, end - c0);
      for (int j = 0; j < lim; j += 8) {
        int i0 = j + qg;
        int i1 = j + 4 + qg;
        int sj0 = __shfl(src, i0 & 63, 64);
        float wj0 = __shfl(wgt, i0 & 63, 64);
        if (i0 >= lim) wj0 = 0.f;
        int sj1 = __shfl(src, i1 & 63, 64);
        float wj1 = __shfl(wgt, i1 & 63, 64);
        if (i1 >= lim) wj1 = 0.f;
        gather8(sj0, wj0, sj1, wj1);
      }
    }
  }

  // combine the four quarter-wave partials
#pragma unroll
  for (int d = 16; d <= 32; d <<= 1) {
    a0 += __shfl_xor(a0, d, 64);
    a1 += __shfl_xor(a1, d, 64);
    a2 += __shfl_xor(a2, d, 64);
    a3 += __shfl_xor(a3, d, 64);
    a4 += __shfl_xor(a4, d, 64);
    a5 += __shfl_xor(a5, d, 64);
    a6 += __shfl_xor(a6, d, 64);
    a7 += __shfl_xor(a7, d, 64);
  }

  if (qg == 0) {
    float4 b0 = *(const float4*)&bias[fl * 8];
    float4 b1 = *(const float4*)&bias[fl * 8 + 4];
    float r0 = a0 + b0.x, r1 = a1 + b0.y, r2 = a2 + b0.z, r3 = a3 + b0.w;
    float r4 = a4 + b1.x, r5 = a5 + b1.y, r6 = a6 + b1.z, r7 = a7 + b1.w;
    if (apply_gelu) {
      r0 = gelu_exact(r0); r1 = gelu_exact(r1);
      r2 = gelu_exact(r2); r3 = gelu_exact(r3);
      r4 = gelu_exact(r4); r5 = gelu_exact(r5);
      r6 = gelu_exact(r6); r7 = gelu_exact(r7);
    }
    *(float4*)&out[(long)dst * DH + fl * 8] = make_float4(r0, r1, r2, r3);
    *(float4*)&out[(long)dst * DH + fl * 8 + 4] = make_float4(r4, r5, r6, r7);
  }
}

// ---------------- masked per-graph mean pooling (batch is sorted) ----------------

__global__ __launch_bounds__(128) void pool_kernel(const float* __restrict__ H,
                                                   const int* __restrict__ batch,
                                                   const int* __restrict__ pos,
                                                   float* __restrict__ sums,
                                                   float* __restrict__ cnt) {
  const int CH = 64;
  int n0 = blockIdx.x * CH;
  int n1 = min(n0 + CH, NN);
  int f = threadIdx.x;
  float acc = 0.f, c = 0.f;
  int g = batch[n0];
  for (int n = n0; n < n1; n++) {
    int gn = batch[n];
    if (gn != g) {
      atomicAdd(&sums[g * DH + f], acc);
      if (f == 0) atomicAdd(&cnt[g], c);
      acc = 0.f; c = 0.f; g = gn;
    }
    if (pos[n]) {
      acc += H[(long)n * DH + f];
      c += 1.f;
    }
  }
  atomicAdd(&sums[g * DH + f], acc);
  if (f == 0) atomicAdd(&cnt[g], c);
}

// ---------------- head ----------------

__global__ __launch_bounds__(128) void head_kernel(const float* __restrict__ sums,
                                                   const float* __restrict__ cnt,
                                                   const float* __restrict__ Wfc,
                                                   const float* __restrict__ bfc,
                                                   float* __restrict__ out) {
  int g = blockIdx.x;
  int f = threadIdx.x;
  float c = fmaxf(cnt[g], 1.f);
  float logit = sums[g * DH + f] / c;
  out[NG + g * DH + f] = logit;
  float gl = gelu_exact(logit) * Wfc[f];
  __shared__ float red[2];
#pragma unroll
  for (int d = 1; d < 64; d <<= 1) gl += __shfl_xor(gl, d, 64);
  int lane = f & 63, w = f >> 6;
  if (lane == 0) red[w] = gl;
  __syncthreads();
  if (f == 0) out[g] = red[0] + red[1] + bfc[0];
}

// ---------------- launch ----------------

extern "C" void kernel_launch(void* const* d_in, const int* in_sizes, int n_in,
                              void* d_out, int out_size, void* d_ws, size_t ws_size,
                              hipStream_t stream) {
  const float* x   = (const float*)d_in[0];
  const int* ei    = (const int*)d_in[1];
  const int* batch = (const int*)d_in[2];
  const int* pos   = (const int*)d_in[3];
  const float* W1  = (const float*)d_in[5];
  const float* as1 = (const float*)d_in[6];
  const float* ad1 = (const float*)d_in[7];
  const float* b1  = (const float*)d_in[8];
  const float* W2  = (const float*)d_in[9];
  const float* as2 = (const float*)d_in[10];
  const float* ad2 = (const float*)d_in[11];
  const float* b2  = (const float*)d_in[12];
  const float* Wfc = (const float*)d_in[13];
  const float* bfc = (const float*)d_in[14];
  float* out = (float*)d_out;

  const int KP1 = 320;
  const int KP2 = 128;
  const int NB_SCAN = (NN + 1023) / 1024;  // 49
  const int BPR = 416;                      // blocks per dst-range (x8 ranges)

  char* ws = (char*)d_ws;
  size_t off = 0;
  auto nxt = [&](size_t b) -> void* {
    size_t p = off;
    off += (b + 255) & ~(size_t)255;
    return (void*)(ws + p);
  };
  int* rowptr = (int*)nxt((NN + 1) * sizeof(int));
  int* cursor = (int*)nxt(NN * sizeof(int));
  int* colA   = (int*)nxt((size_t)(EE + NN) * sizeof(int));
  int* bsum   = (int*)nxt((NB_SCAN + 1) * sizeof(int));
  int* boff   = (int*)nxt((NB_SCAN + 1) * sizeof(int));
  float* aS   = (float*)nxt((size_t)2 * NN * sizeof(float));
  float* aD   = aS + NN;
  unsigned short* bufAb = (unsigned short*)nxt((size_t)NN * DH * sizeof(short));
  float* bufB = (float*)nxt((size_t)NN * DH * sizeof(float));
  float* sums = (float*)nxt((size_t)(NG * DH + NG) * sizeof(float));
  float* cnt  = sums + NG * DH;
  unsigned short* Bt1h = (unsigned short*)nxt((size_t)128 * KP1 * sizeof(short));
  unsigned short* Bt1l = (unsigned short*)nxt((size_t)128 * KP1 * sizeof(short));
  unsigned short* Bt2h = (unsigned short*)nxt((size_t)128 * KP2 * sizeof(short));
  unsigned short* Bt2l = (unsigned short*)nxt((size_t)128 * KP2 * sizeof(short));

  hipMemsetAsync(cursor, 0, NN * sizeof(int), stream);
  hipMemsetAsync(sums, 0, (NG * DH + NG) * sizeof(float), stream);

  convert_bt_kernel<<<(128 * KP1 + 255) / 256, 256, 0, stream>>>(W1, Bt1h, Bt1l, DIN, KP1);
  convert_bt_kernel<<<(128 * KP2 + 255) / 256, 256, 0, stream>>>(W2, Bt2h, Bt2l, DH, KP2);

  count_part_kernel<<<8 * BPR, 256, 0, stream>>>(ei, cursor, BPR);
  scan_part_kernel<<<NB_SCAN, 1024, 0, stream>>>(cursor, rowptr, bsum);
  scan_sums_kernel<<<1, 64, 0, stream>>>(bsum, boff, NB_SCAN);
  scan_add_kernel<<<(NN + 1 + 255) / 256, 256, 0, stream>>>(rowptr, boff, cursor, NB_SCAN);
  scatter_part_kernel<<<8 * BPR, 256, 0, stream>>>(ei, cursor, colA, BPR);

  const int gblocks = (NN + 63) / 64;
  // layer 1
  gemm_mfma_kernel<<<gblocks, 256, 0, stream>>>(x, Bt1h, Bt1l, bufAb, NN, DIN, KP1,
                                                as1, ad1, aS, aD);
  aggregate_kernel<<<(NN + 3) / 4, 256, 0, stream>>>(rowptr, colA, aS, aD, bufAb, b1, bufB, 1);
  // layer 2
  gemm_mfma_kernel<<<gblocks, 256, 0, stream>>>(bufB, Bt2h, Bt2l, bufAb, NN, DH, KP2,
                                                as2, ad2, aS, aD);
  aggregate_kernel<<<(NN + 3) / 4, 256, 0, stream>>>(rowptr, colA, aS, aD, bufAb, b2, bufB, 0);
  // pooling + head
  pool_kernel<<<(NN + 63) / 64, 128, 0, stream>>>(bufB, batch, pos, sums, cnt);
  head_kernel<<<NG, 128, 0, stream>>>(sums, cnt, Wfc, bfc, out);
}

// Round 14
// 331.779 us; speedup vs baseline: 1.2296x; 1.0270x over previous
//
#include <hip/hip_runtime.h>
#include <math.h>

#define NN 50000
#define EE 800000
#define DIN 300
#define DH 128
#define NG 128
#define RSIZE 6250  // NN/8 dst-range per XCD partition

typedef __attribute__((ext_vector_type(8))) short short8;
typedef __attribute__((ext_vector_type(4))) float floatx4;

__device__ __forceinline__ float gelu_exact(float x) {
  return 0.5f * x * (1.0f + erff(x * 0.7071067811865476f));
}

__device__ __forceinline__ void split_bf16(float v, unsigned short& hi, unsigned short& lo) {
  unsigned int u = __float_as_uint(v);
  hi = (unsigned short)(u >> 16);
  float fh = __uint_as_float((unsigned int)hi << 16);
  lo = (unsigned short)(__float_as_uint(v - fh) >> 16);
}

__device__ __forceinline__ unsigned short f2bf_rne(float x) {
  unsigned int u = __float_as_uint(x);
  unsigned int r = (u + 0x7FFFu + ((u >> 16) & 1u)) >> 16;
  return (unsigned short)r;
}

__device__ __forceinline__ float bf_lo(unsigned u) { return __uint_as_float(u << 16); }
__device__ __forceinline__ float bf_hi(unsigned u) { return __uint_as_float(u & 0xFFFF0000u); }

// async 16B global->LDS DMA (gfx950). LDS dest = wave-uniform base + lane*16.
__device__ __forceinline__ void async_ld16(void* lds, const void* g) {
  __builtin_amdgcn_global_load_lds(
      (const __attribute__((address_space(1))) unsigned int*)(unsigned long long)g,
      (__attribute__((address_space(3))) unsigned int*)(unsigned int)(unsigned long long)lds,
      16, 0, 0);
}

// ---------------- CSR build (XCD-partitioned by dst range) ----------------

__global__ __launch_bounds__(256) void count_part_kernel(const int* __restrict__ ei,
                                                         int* __restrict__ deg,
                                                         int blocksPerRange) {
  const int r = blockIdx.x & 7;
  const int t = blockIdx.x >> 3;
  const int lo = r * RSIZE, hi = lo + RSIZE;
  const int total = EE + NN;
  const int step = blocksPerRange * 256;
  for (int e0 = t * 256; e0 < total; e0 += step) {
    int e = e0 + threadIdx.x;
    if (e < total) {
      int d = (e < EE) ? ei[EE + e] : (e - EE);
      if (d >= lo && d < hi) atomicAdd(&deg[d], 1);
    }
  }
}

__global__ __launch_bounds__(1024) void scan_part_kernel(const int* __restrict__ deg,
                                                         int* __restrict__ rowptr,
                                                         int* __restrict__ bsum) {
  __shared__ int wsum[16];
  const int tid = threadIdx.x;
  const int lane = tid & 63;
  const int wid = tid >> 6;
  int idx = blockIdx.x * 1024 + tid;
  int v = (idx < NN) ? deg[idx] : 0;
  int x = v;
#pragma unroll
  for (int d = 1; d < 64; d <<= 1) {
    int y = __shfl_up(x, d, 64);
    if (lane >= d) x += y;
  }
  if (lane == 63) wsum[wid] = x;
  __syncthreads();
  if (wid == 0) {
    int s = (lane < 16) ? wsum[lane] : 0;
#pragma unroll
    for (int d = 1; d < 16; d <<= 1) {
      int y = __shfl_up(s, d, 64);
      if (lane >= d) s += y;
    }
    if (lane < 16) wsum[lane] = s;
  }
  __syncthreads();
  int woff = (wid > 0) ? wsum[wid - 1] : 0;
  int incl = x + woff;
  if (idx < NN) rowptr[idx] = incl - v;
  if (tid == 1023) bsum[blockIdx.x] = incl;
}

// scan_add now computes the (tiny, 49-entry) block-sum prefix scan itself in
// its first wave (redundantly per block) -> scan_sums launch deleted.
__global__ __launch_bounds__(256) void scan_add_kernel(int* __restrict__ rowptr,
                                                       const int* __restrict__ bsum,
                                                       int* __restrict__ cursor, int nb) {
  __shared__ int boff_s[64];  // exclusive offsets [nb] + total at [nb]
  const int tid = threadIdx.x;
  if (tid < 64) {
    int lane = tid;
    int v = (lane < nb) ? bsum[lane] : 0;
    int x = v;
#pragma unroll
    for (int d = 1; d < 64; d <<= 1) {
      int y = __shfl_up(x, d, 64);
      if (lane >= d) x += y;
    }
    if (lane < nb) boff_s[lane] = x - v;
    if (lane == nb - 1) boff_s[nb] = x;
  }
  __syncthreads();
  int i = blockIdx.x * 256 + tid;
  if (i < NN) {
    int r = rowptr[i] + boff_s[i >> 10];
    rowptr[i] = r;
    cursor[i] = r;
  } else if (i == NN) {
    rowptr[NN] = boff_s[nb];
  }
}

__global__ __launch_bounds__(256) void scatter_part_kernel(const int* __restrict__ ei,
                                                           int* __restrict__ cursor,
                                                           int* __restrict__ colA,
                                                           int blocksPerRange) {
  const int r = blockIdx.x & 7;
  const int t = blockIdx.x >> 3;
  const int lo = r * RSIZE, hi = lo + RSIZE;
  const int total = EE + NN;
  const int step = blocksPerRange * 256;
  for (int e0 = t * 256; e0 < total; e0 += step) {
    int e = e0 + threadIdx.x;
    if (e < total) {
      int d = (e < EE) ? ei[EE + e] : (e - EE);
      if (d >= lo && d < hi) {
        int s = (e < EE) ? ei[e] : d;
        int p = atomicAdd(&cursor[d], 1);
        colA[p] = s;
      }
    }
  }
}

// ---------------- B pre-transpose + split (both layers, one launch) ----------------

__global__ __launch_bounds__(256) void convert_bt2_kernel(
    const float* __restrict__ B1, unsigned short* __restrict__ B1h,
    unsigned short* __restrict__ B1l, int K1, int Kp1, int nblk1,
    const float* __restrict__ B2, unsigned short* __restrict__ B2h,
    unsigned short* __restrict__ B2l, int K2, int Kp2) {
  const float* B;
  unsigned short *Bh, *Bl;
  int K, Kpad, i;
  if ((int)blockIdx.x < nblk1) {
    B = B1; Bh = B1h; Bl = B1l; K = K1; Kpad = Kp1;
    i = blockIdx.x * 256 + threadIdx.x;
  } else {
    B = B2; Bh = B2h; Bl = B2l; K = K2; Kpad = Kp2;
    i = (blockIdx.x - nblk1) * 256 + threadIdx.x;
  }
  int n = i / Kpad, k = i % Kpad;
  if (n >= 128) return;
  float v = (k < K) ? B[(long)k * 128 + n] : 0.f;
  unsigned short h, l;
  split_bf16(v, h, l);
  Bh[(long)n * Kpad + k] = h;
  Bl[(long)n * Kpad + k] = l;
}

// ---------------- MFMA split-bf16 GEMM + fused attention row-dots ----------------
// Round-9 design (best measured: ~42us GEMM1, FETCH 33MB): BM=64, BN=128, BK=32.

__global__ __launch_bounds__(256) void gemm_mfma_kernel(
    const float* __restrict__ A,
    const unsigned short* __restrict__ Bth, const unsigned short* __restrict__ Btl,
    unsigned short* __restrict__ C, int M, int K, int Kpad,
    const float* __restrict__ avs, const float* __restrict__ avd,
    float* __restrict__ aS, float* __restrict__ aD) {
  __shared__ __align__(16) unsigned short Bls[2][2][128 * 32];  // [buf][plane][n*32+k]

  const int tid = threadIdx.x;
  const int lane = tid & 63;
  const int w = tid >> 6;
  const int q = lane >> 4;
  const int m16 = lane & 15;
  const int row0 = blockIdx.x * 64;
  const int myrow = row0 + w * 16 + m16;
  const bool rok = myrow < M;
  const long abase = (long)myrow * K;

  const int rl = lane >> 2, qq0 = lane & 3;
  const int nb0 = w * 16 + rl;
  const int nb1 = 64 + w * 16 + rl;
  const long boff0 = (long)nb0 * Kpad + (long)((qq0 ^ ((nb0 >> 1) & 3)) * 8);
  const long boff1 = (long)nb1 * Kpad + (long)((qq0 ^ ((nb1 >> 1) & 3)) * 8);

  floatx4 acc[8];
#pragma unroll
  for (int i = 0; i < 8; i++) acc[i] = (floatx4)(0.f);

  const int nsteps = Kpad / 32;

  float4 vA0, vA1, nA0, nA1;
  nA0 = nA1 = make_float4(0.f, 0.f, 0.f, 0.f);

  auto stageB = [&](int s, int nb) {
    const int k0 = s * 32;
    async_ld16(&Bls[nb][0][(w * 16) * 32], Bth + boff0 + k0);
    async_ld16(&Bls[nb][0][(64 + w * 16) * 32], Bth + boff1 + k0);
    async_ld16(&Bls[nb][1][(w * 16) * 32], Btl + boff0 + k0);
    async_ld16(&Bls[nb][1][(64 + w * 16) * 32], Btl + boff1 + k0);
  };
  auto loadA = [&](int s, float4& x0, float4& x1) {
    const int k0 = s * 32 + q * 8;
    x0 = make_float4(0.f, 0.f, 0.f, 0.f);
    x1 = x0;
    if (rok) {
      if (k0 + 4 <= K) x0 = *(const float4*)&A[abase + k0];
      if (k0 + 8 <= K) x1 = *(const float4*)&A[abase + k0 + 4];
    }
  };

  stageB(0, 0);
  loadA(0, vA0, vA1);
  __syncthreads();

  for (int s = 0; s < nsteps; s++) {
    const int cur = s & 1;
    if (s + 1 < nsteps) {
      stageB(s + 1, 1 ^ cur);
      loadA(s + 1, nA0, nA1);
    }
    float av[8] = {vA0.x, vA0.y, vA0.z, vA0.w, vA1.x, vA1.y, vA1.z, vA1.w};
    union {
      unsigned u[4];
      short8 s8;
    } Uh, Ul;
#pragma unroll
    for (int i = 0; i < 4; i++) {
      unsigned short ha, la, hb, lb;
      split_bf16(av[2 * i], ha, la);
      split_bf16(av[2 * i + 1], hb, lb);
      Uh.u[i] = (unsigned)ha | ((unsigned)hb << 16);
      Ul.u[i] = (unsigned)la | ((unsigned)lb << 16);
    }
    short8 afh = Uh.s8, afl = Ul.s8;
#pragma unroll
    for (int ct = 0; ct < 8; ct++) {
      int n = ct * 16 + m16;
      int qv = (q ^ ((n >> 1) & 3)) * 8;
      short8 bfh = *(const short8*)&Bls[cur][0][n * 32 + qv];
      short8 bfl = *(const short8*)&Bls[cur][1][n * 32 + qv];
      acc[ct] = __builtin_amdgcn_mfma_f32_16x16x32_bf16(afh, bfh, acc[ct], 0, 0, 0);
      acc[ct] = __builtin_amdgcn_mfma_f32_16x16x32_bf16(afh, bfl, acc[ct], 0, 0, 0);
      acc[ct] = __builtin_amdgcn_mfma_f32_16x16x32_bf16(afl, bfh, acc[ct], 0, 0, 0);
    }
    vA0 = nA0;
    vA1 = nA1;
    __syncthreads();
  }

  float avs_r[8], avd_r[8];
#pragma unroll
  for (int ct = 0; ct < 8; ct++) {
    avs_r[ct] = avs[ct * 16 + m16];
    avd_r[ct] = avd[ct * 16 + m16];
  }
#pragma unroll
  for (int reg = 0; reg < 4; reg++) {
    int grow = row0 + w * 16 + q * 4 + reg;
    bool ok = grow < M;
    float ps = 0.f, pd = 0.f;
#pragma unroll
    for (int ct = 0; ct < 8; ct++) {
      float c = acc[ct][reg];
      if (ok) C[(long)grow * 128 + ct * 16 + m16] = f2bf_rne(c);
      ps = fmaf(c, avs_r[ct], ps);
      pd = fmaf(c, avd_r[ct], pd);
    }
#pragma unroll
    for (int d = 1; d < 16; d <<= 1) {
      ps += __shfl_xor(ps, d, 64);
      pd += __shfl_xor(pd, d, 64);
    }
    if (m16 == 0 && ok) {
      aS[grow] = ps;
      aD[grow] = pd;
    }
  }
}

// ---------------- softmax attention + aggregation: one WAVE per dst ----------------
// QUARTER-wave owns one edge: 16 lanes x uint4(16B) = 256B row, 4 edges per
// load instruction, unroll 2 => 8 edges in flight per wave.

__global__ __launch_bounds__(256) void aggregate_kernel(const int* __restrict__ rowptr,
                                                        const int* __restrict__ colA,
                                                        const float* __restrict__ aS,
                                                        const float* __restrict__ aD,
                                                        const unsigned short* __restrict__ Hb,
                                                        const float* __restrict__ bias,
                                                        float* __restrict__ out,
                                                        int apply_gelu) {
  const int lane = threadIdx.x & 63;
  const int dst = blockIdx.x * 4 + (threadIdx.x >> 6);
  if (dst >= NN) return;
  const int start = rowptr[dst];
  const int end = rowptr[dst + 1];
  const int deg = end - start;
  const float ad = aD[dst];
  const int qg = lane >> 4;   // quarter-wave (edge slot)
  const int fl = lane & 15;   // feature octet index: feats fl*8..fl*8+7

  float a0 = 0.f, a1 = 0.f, a2 = 0.f, a3 = 0.f;
  float a4 = 0.f, a5 = 0.f, a6 = 0.f, a7 = 0.f;

  auto gather8 = [&](int sj0, float wj0, int sj1, float wj1) {
    uint4 u0 = *(const uint4*)&Hb[(long)sj0 * DH + fl * 8];
    uint4 u1 = *(const uint4*)&Hb[(long)sj1 * DH + fl * 8];
    a0 = fmaf(wj0, bf_lo(u0.x), a0);
    a1 = fmaf(wj0, bf_hi(u0.x), a1);
    a2 = fmaf(wj0, bf_lo(u0.y), a2);
    a3 = fmaf(wj0, bf_hi(u0.y), a3);
    a4 = fmaf(wj0, bf_lo(u0.z), a4);
    a5 = fmaf(wj0, bf_hi(u0.z), a5);
    a6 = fmaf(wj0, bf_lo(u0.w), a6);
    a7 = fmaf(wj0, bf_hi(u0.w), a7);
    a0 = fmaf(wj1, bf_lo(u1.x), a0);
    a1 = fmaf(wj1, bf_hi(u1.x), a1);
    a2 = fmaf(wj1, bf_lo(u1.y), a2);
    a3 = fmaf(wj1, bf_hi(u1.y), a3);
    a4 = fmaf(wj1, bf_lo(u1.z), a4);
    a5 = fmaf(wj1, bf_hi(u1.z), a5);
    a6 = fmaf(wj1, bf_lo(u1.w), a6);
    a7 = fmaf(wj1, bf_hi(u1.w), a7);
  };

  if (deg <= 64) {
    int src = 0;
    float e = -__builtin_inff();
    if (lane < deg) {
      src = colA[start + lane];
      float v = aS[src] + ad;
      e = (v > 0.f) ? v : 0.2f * v;
    }
    float mx = e;
#pragma unroll
    for (int d = 1; d < 64; d <<= 1) mx = fmaxf(mx, __shfl_xor(mx, d, 64));
    float ew = (lane < deg) ? expf(e - mx) : 0.f;
    float ss = ew;
#pragma unroll
    for (int d = 1; d < 64; d <<= 1) ss += __shfl_xor(ss, d, 64);
    float wgt = ew * (1.f / ss);
    for (int j = 0; j < deg; j += 8) {
      int i0 = j + qg;
      int i1 = j + 4 + qg;
      int sj0 = __shfl(src, i0 & 63, 64);
      float wj0 = __shfl(wgt, i0 & 63, 64);
      if (i0 >= deg) wj0 = 0.f;
      int sj1 = __shfl(src, i1 & 63, 64);
      float wj1 = __shfl(wgt, i1 & 63, 64);
      if (i1 >= deg) wj1 = 0.f;
      gather8(sj0, wj0, sj1, wj1);
    }
  } else {
    float m = -__builtin_inff(), ssum = 0.f;
    for (int c0 = start; c0 < end; c0 += 64) {
      int i = c0 + lane;
      float e = -__builtin_inff();
      if (i < end) {
        int s = colA[i];
        float v = aS[s] + ad;
        e = (v > 0.f) ? v : 0.2f * v;
      }
      float cm = e;
#pragma unroll
      for (int d = 1; d < 64; d <<= 1) cm = fmaxf(cm, __shfl_xor(cm, d, 64));
      float ce = (i < end) ? expf(e - cm) : 0.f;
      float cs = ce;
#pragma unroll
      for (int d = 1; d < 64; d <<= 1) cs += __shfl_xor(cs, d, 64);
      float nm = fmaxf(m, cm);
      ssum = ssum * expf(m - nm) + cs * expf(cm - nm);
      m = nm;
    }
    float inv = 1.f / ssum;
    for (int c0 = start; c0 < end; c0 += 64) {
      int i = c0 + lane;
      int src = 0;
      float wgt = 0.f;
      if (i < end) {
        src = colA[i];
        float v = aS[src] + ad;
        float e = (v > 0.f) ? v : 0.2f * v;
        wgt = expf(e - m) * inv;
      }
      int lim = min(64, end - c0);
      for (int j = 0; j < lim; j += 8) {
        int i0 = j + qg;
        int i1 = j + 4 + qg;
        int sj0 = __shfl(src, i0 & 63, 64);
        float wj0 = __shfl(wgt, i0 & 63, 64);
        if (i0 >= lim) wj0 = 0.f;
        int sj1 = __shfl(src, i1 & 63, 64);
        float wj1 = __shfl(wgt, i1 & 63, 64);
        if (i1 >= lim) wj1 = 0.f;
        gather8(sj0, wj0, sj1, wj1);
      }
    }
  }

#pragma unroll
  for (int d = 16; d <= 32; d <<= 1) {
    a0 += __shfl_xor(a0, d, 64);
    a1 += __shfl_xor(a1, d, 64);
    a2 += __shfl_xor(a2, d, 64);
    a3 += __shfl_xor(a3, d, 64);
    a4 += __shfl_xor(a4, d, 64);
    a5 += __shfl_xor(a5, d, 64);
    a6 += __shfl_xor(a6, d, 64);
    a7 += __shfl_xor(a7, d, 64);
  }

  if (qg == 0) {
    float4 b0 = *(const float4*)&bias[fl * 8];
    float4 b1 = *(const float4*)&bias[fl * 8 + 4];
    float r0 = a0 + b0.x, r1 = a1 + b0.y, r2 = a2 + b0.z, r3 = a3 + b0.w;
    float r4 = a4 + b1.x, r5 = a5 + b1.y, r6 = a6 + b1.z, r7 = a7 + b1.w;
    if (apply_gelu) {
      r0 = gelu_exact(r0); r1 = gelu_exact(r1);
      r2 = gelu_exact(r2); r3 = gelu_exact(r3);
      r4 = gelu_exact(r4); r5 = gelu_exact(r5);
      r6 = gelu_exact(r6); r7 = gelu_exact(r7);
    }
    *(float4*)&out[(long)dst * DH + fl * 8] = make_float4(r0, r1, r2, r3);
    *(float4*)&out[(long)dst * DH + fl * 8 + 4] = make_float4(r4, r5, r6, r7);
  }
}

// ---------------- masked per-graph mean pooling (batch is sorted) ----------------
// 4-row batched loads: 4 independent H-row reads in flight per iteration
// (was: 64 serial dependent loads -> pure latency ~9us for a 25MB read).

__global__ __launch_bounds__(128) void pool_kernel(const float* __restrict__ H,
                                                   const int* __restrict__ batch,
                                                   const int* __restrict__ pos,
                                                   float* __restrict__ sums,
                                                   float* __restrict__ cnt) {
  const int CH = 64;
  int n0 = blockIdx.x * CH;
  int n1 = min(n0 + CH, NN);
  int f = threadIdx.x;
  float acc = 0.f, c = 0.f;
  int g = batch[n0];
  for (int n = n0; n < n1; n += 4) {
    // issue 4 independent row loads + metadata (NN % 4 == 0, CH % 4 == 0)
    float h0 = H[(long)(n + 0) * DH + f];
    float h1 = H[(long)(n + 1) * DH + f];
    float h2 = H[(long)(n + 2) * DH + f];
    float h3 = H[(long)(n + 3) * DH + f];
    int g0 = batch[n + 0], g1 = batch[n + 1], g2 = batch[n + 2], g3 = batch[n + 3];
    int p0 = pos[n + 0], p1 = pos[n + 1], p2 = pos[n + 2], p3 = pos[n + 3];
    float hv[4] = {h0, h1, h2, h3};
    int gv[4] = {g0, g1, g2, g3};
    int pv[4] = {p0, p1, p2, p3};
#pragma unroll
    for (int i = 0; i < 4; i++) {
      if (gv[i] != g) {
        atomicAdd(&sums[g * DH + f], acc);
        if (f == 0) atomicAdd(&cnt[g], c);
        acc = 0.f; c = 0.f; g = gv[i];
      }
      if (pv[i]) {
        acc += hv[i];
        c += 1.f;
      }
    }
  }
  atomicAdd(&sums[g * DH + f], acc);
  if (f == 0) atomicAdd(&cnt[g], c);
}

// ---------------- head ----------------

__global__ __launch_bounds__(128) void head_kernel(const float* __restrict__ sums,
                                                   const float* __restrict__ cnt,
                                                   const float* __restrict__ Wfc,
                                                   const float* __restrict__ bfc,
                                                   float* __restrict__ out) {
  int g = blockIdx.x;
  int f = threadIdx.x;
  float c = fmaxf(cnt[g], 1.f);
  float logit = sums[g * DH + f] / c;
  out[NG + g * DH + f] = logit;
  float gl = gelu_exact(logit) * Wfc[f];
  __shared__ float red[2];
#pragma unroll
  for (int d = 1; d < 64; d <<= 1) gl += __shfl_xor(gl, d, 64);
  int lane = f & 63, w = f >> 6;
  if (lane == 0) red[w] = gl;
  __syncthreads();
  if (f == 0) out[g] = red[0] + red[1] + bfc[0];
}

// ---------------- launch ----------------

extern "C" void kernel_launch(void* const* d_in, const int* in_sizes, int n_in,
                              void* d_out, int out_size, void* d_ws, size_t ws_size,
                              hipStream_t stream) {
  const float* x   = (const float*)d_in[0];
  const int* ei    = (const int*)d_in[1];
  const int* batch = (const int*)d_in[2];
  const int* pos   = (const int*)d_in[3];
  const float* W1  = (const float*)d_in[5];
  const float* as1 = (const float*)d_in[6];
  const float* ad1 = (const float*)d_in[7];
  const float* b1  = (const float*)d_in[8];
  const float* W2  = (const float*)d_in[9];
  const float* as2 = (const float*)d_in[10];
  const float* ad2 = (const float*)d_in[11];
  const float* b2  = (const float*)d_in[12];
  const float* Wfc = (const float*)d_in[13];
  const float* bfc = (const float*)d_in[14];
  float* out = (float*)d_out;

  const int KP1 = 320;
  const int KP2 = 128;
  const int NB_SCAN = (NN + 1023) / 1024;  // 49
  const int BPR = 416;                      // blocks per dst-range (x8 ranges)

  char* ws = (char*)d_ws;
  size_t off = 0;
  auto nxt = [&](size_t b) -> void* {
    size_t p = off;
    off += (b + 255) & ~(size_t)255;
    return (void*)(ws + p);
  };
  int* rowptr = (int*)nxt((NN + 1) * sizeof(int));
  int* cursor = (int*)nxt(NN * sizeof(int));
  int* colA   = (int*)nxt((size_t)(EE + NN) * sizeof(int));
  int* bsum   = (int*)nxt((NB_SCAN + 1) * sizeof(int));
  float* aS   = (float*)nxt((size_t)2 * NN * sizeof(float));
  float* aD   = aS + NN;
  unsigned short* bufAb = (unsigned short*)nxt((size_t)NN * DH * sizeof(short));
  float* bufB = (float*)nxt((size_t)NN * DH * sizeof(float));
  float* sums = (float*)nxt((size_t)(NG * DH + NG) * sizeof(float));
  float* cnt  = sums + NG * DH;
  unsigned short* Bt1h = (unsigned short*)nxt((size_t)128 * KP1 * sizeof(short));
  unsigned short* Bt1l = (unsigned short*)nxt((size_t)128 * KP1 * sizeof(short));
  unsigned short* Bt2h = (unsigned short*)nxt((size_t)128 * KP2 * sizeof(short));
  unsigned short* Bt2l = (unsigned short*)nxt((size_t)128 * KP2 * sizeof(short));

  hipMemsetAsync(cursor, 0, NN * sizeof(int), stream);
  hipMemsetAsync(sums, 0, (NG * DH + NG) * sizeof(float), stream);

  const int cb1 = (128 * KP1 + 255) / 256;
  const int cb2 = (128 * KP2 + 255) / 256;
  convert_bt2_kernel<<<cb1 + cb2, 256, 0, stream>>>(W1, Bt1h, Bt1l, DIN, KP1, cb1,
                                                    W2, Bt2h, Bt2l, DH, KP2);

  count_part_kernel<<<8 * BPR, 256, 0, stream>>>(ei, cursor, BPR);
  scan_part_kernel<<<NB_SCAN, 1024, 0, stream>>>(cursor, rowptr, bsum);
  scan_add_kernel<<<(NN + 1 + 255) / 256, 256, 0, stream>>>(rowptr, bsum, cursor, NB_SCAN);
  scatter_part_kernel<<<8 * BPR, 256, 0, stream>>>(ei, cursor, colA, BPR);

  const int gblocks = (NN + 63) / 64;
  // layer 1
  gemm_mfma_kernel<<<gblocks, 256, 0, stream>>>(x, Bt1h, Bt1l, bufAb, NN, DIN, KP1,
                                                as1, ad1, aS, aD);
  aggregate_kernel<<<(NN + 3) / 4, 256, 0, stream>>>(rowptr, colA, aS, aD, bufAb, b1, bufB, 1);
  // layer 2
  gemm_mfma_kernel<<<gblocks, 256, 0, stream>>>(bufB, Bt2h, Bt2l, bufAb, NN, DH, KP2,
                                                as2, ad2, aS, aD);
  aggregate_kernel<<<(NN + 3) / 4, 256, 0, stream>>>(rowptr, colA, aS, aD, bufAb, b2, bufB, 0);
  // pooling + head
  pool_kernel<<<(NN + 63) / 64, 128, 0, stream>>>(bufB, batch, pos, sums, cnt);
  head_kernel<<<NG, 128, 0, stream>>>(sums, cnt, Wfc, bfc, out);
}

// Round 15
// 321.817 us; speedup vs baseline: 1.2676x; 1.0310x over previous
//
#include <hip/hip_runtime.h>
#include <math.h>

#define NN 50000
#define EE 800000
#define DIN 300
#define DH 128
#define NG 128
#define RSIZE 6250  // NN/8 dst-range per XCD partition

typedef __attribute__((ext_vector_type(8))) short short8;
typedef __attribute__((ext_vector_type(4))) float floatx4;

__device__ __forceinline__ float gelu_exact(float x) {
  return 0.5f * x * (1.0f + erff(x * 0.7071067811865476f));
}

__device__ __forceinline__ void split_bf16(float v, unsigned short& hi, unsigned short& lo) {
  unsigned int u = __float_as_uint(v);
  hi = (unsigned short)(u >> 16);
  float fh = __uint_as_float((unsigned int)hi << 16);
  lo = (unsigned short)(__float_as_uint(v - fh) >> 16);
}

__device__ __forceinline__ unsigned short f2bf_rne(float x) {
  unsigned int u = __float_as_uint(x);
  unsigned int r = (u + 0x7FFFu + ((u >> 16) & 1u)) >> 16;
  return (unsigned short)r;
}

__device__ __forceinline__ float bf_lo(unsigned u) { return __uint_as_float(u << 16); }
__device__ __forceinline__ float bf_hi(unsigned u) { return __uint_as_float(u & 0xFFFF0000u); }

// async 16B global->LDS DMA (gfx950). LDS dest = wave-uniform base + lane*16.
__device__ __forceinline__ void async_ld16(void* lds, const void* g) {
  __builtin_amdgcn_global_load_lds(
      (const __attribute__((address_space(1))) unsigned int*)(unsigned long long)g,
      (__attribute__((address_space(3))) unsigned int*)(unsigned int)(unsigned long long)lds,
      16, 0, 0);
}

// ---------------- CSR build (XCD-partitioned by dst range) ----------------

__global__ __launch_bounds__(256) void count_part_kernel(const int* __restrict__ ei,
                                                         int* __restrict__ deg,
                                                         int blocksPerRange) {
  const int r = blockIdx.x & 7;
  const int t = blockIdx.x >> 3;
  const int lo = r * RSIZE, hi = lo + RSIZE;
  const int total = EE + NN;
  const int step = blocksPerRange * 256;
  for (int e0 = t * 256; e0 < total; e0 += step) {
    int e = e0 + threadIdx.x;
    if (e < total) {
      int d = (e < EE) ? ei[EE + e] : (e - EE);
      if (d >= lo && d < hi) atomicAdd(&deg[d], 1);
    }
  }
}

__global__ __launch_bounds__(1024) void scan_part_kernel(const int* __restrict__ deg,
                                                         int* __restrict__ rowptr,
                                                         int* __restrict__ bsum) {
  __shared__ int wsum[16];
  const int tid = threadIdx.x;
  const int lane = tid & 63;
  const int wid = tid >> 6;
  int idx = blockIdx.x * 1024 + tid;
  int v = (idx < NN) ? deg[idx] : 0;
  int x = v;
#pragma unroll
  for (int d = 1; d < 64; d <<= 1) {
    int y = __shfl_up(x, d, 64);
    if (lane >= d) x += y;
  }
  if (lane == 63) wsum[wid] = x;
  __syncthreads();
  if (wid == 0) {
    int s = (lane < 16) ? wsum[lane] : 0;
#pragma unroll
    for (int d = 1; d < 16; d <<= 1) {
      int y = __shfl_up(s, d, 64);
      if (lane >= d) s += y;
    }
    if (lane < 16) wsum[lane] = s;
  }
  __syncthreads();
  int woff = (wid > 0) ? wsum[wid - 1] : 0;
  int incl = x + woff;
  if (idx < NN) rowptr[idx] = incl - v;
  if (tid == 1023) bsum[blockIdx.x] = incl;
}

// scan_add computes the (tiny, 49-entry) block-sum prefix scan itself.
__global__ __launch_bounds__(256) void scan_add_kernel(int* __restrict__ rowptr,
                                                       const int* __restrict__ bsum,
                                                       int* __restrict__ cursor, int nb) {
  __shared__ int boff_s[64];
  const int tid = threadIdx.x;
  if (tid < 64) {
    int lane = tid;
    int v = (lane < nb) ? bsum[lane] : 0;
    int x = v;
#pragma unroll
    for (int d = 1; d < 64; d <<= 1) {
      int y = __shfl_up(x, d, 64);
      if (lane >= d) x += y;
    }
    if (lane < nb) boff_s[lane] = x - v;
    if (lane == nb - 1) boff_s[nb] = x;
  }
  __syncthreads();
  int i = blockIdx.x * 256 + tid;
  if (i < NN) {
    int r = rowptr[i] + boff_s[i >> 10];
    rowptr[i] = r;
    cursor[i] = r;
  } else if (i == NN) {
    rowptr[NN] = boff_s[nb];
  }
}

__global__ __launch_bounds__(256) void scatter_part_kernel(const int* __restrict__ ei,
                                                           int* __restrict__ cursor,
                                                           int* __restrict__ colA,
                                                           int blocksPerRange) {
  const int r = blockIdx.x & 7;
  const int t = blockIdx.x >> 3;
  const int lo = r * RSIZE, hi = lo + RSIZE;
  const int total = EE + NN;
  const int step = blocksPerRange * 256;
  for (int e0 = t * 256; e0 < total; e0 += step) {
    int e = e0 + threadIdx.x;
    if (e < total) {
      int d = (e < EE) ? ei[EE + e] : (e - EE);
      if (d >= lo && d < hi) {
        int s = (e < EE) ? ei[e] : d;
        int p = atomicAdd(&cursor[d], 1);
        colA[p] = s;
      }
    }
  }
}

// ---------------- B pre-transpose + split (both layers, one launch) ----------------

__global__ __launch_bounds__(256) void convert_bt2_kernel(
    const float* __restrict__ B1, unsigned short* __restrict__ B1h,
    unsigned short* __restrict__ B1l, int K1, int Kp1, int nblk1,
    const float* __restrict__ B2, unsigned short* __restrict__ B2h,
    unsigned short* __restrict__ B2l, int K2, int Kp2) {
  const float* B;
  unsigned short *Bh, *Bl;
  int K, Kpad, i;
  if ((int)blockIdx.x < nblk1) {
    B = B1; Bh = B1h; Bl = B1l; K = K1; Kpad = Kp1;
    i = blockIdx.x * 256 + threadIdx.x;
  } else {
    B = B2; Bh = B2h; Bl = B2l; K = K2; Kpad = Kp2;
    i = (blockIdx.x - nblk1) * 256 + threadIdx.x;
  }
  int n = i / Kpad, k = i % Kpad;
  if (n >= 128) return;
  float v = (k < K) ? B[(long)k * 128 + n] : 0.f;
  unsigned short h, l;
  split_bf16(v, h, l);
  Bh[(long)n * Kpad + k] = h;
  Bl[(long)n * Kpad + k] = l;
}

// ---------------- MFMA split-bf16 GEMM + fused attention row-dots ----------------
// Round-9 design (best measured: ~42us GEMM1, FETCH 33MB): BM=64, BN=128, BK=32.

__global__ __launch_bounds__(256) void gemm_mfma_kernel(
    const float* __restrict__ A,
    const unsigned short* __restrict__ Bth, const unsigned short* __restrict__ Btl,
    unsigned short* __restrict__ C, int M, int K, int Kpad,
    const float* __restrict__ avs, const float* __restrict__ avd,
    float* __restrict__ aS, float* __restrict__ aD) {
  __shared__ __align__(16) unsigned short Bls[2][2][128 * 32];  // [buf][plane][n*32+k]

  const int tid = threadIdx.x;
  const int lane = tid & 63;
  const int w = tid >> 6;
  const int q = lane >> 4;
  const int m16 = lane & 15;
  const int row0 = blockIdx.x * 64;
  const int myrow = row0 + w * 16 + m16;
  const bool rok = myrow < M;
  const long abase = (long)myrow * K;

  const int rl = lane >> 2, qq0 = lane & 3;
  const int nb0 = w * 16 + rl;
  const int nb1 = 64 + w * 16 + rl;
  const long boff0 = (long)nb0 * Kpad + (long)((qq0 ^ ((nb0 >> 1) & 3)) * 8);
  const long boff1 = (long)nb1 * Kpad + (long)((qq0 ^ ((nb1 >> 1) & 3)) * 8);

  floatx4 acc[8];
#pragma unroll
  for (int i = 0; i < 8; i++) acc[i] = (floatx4)(0.f);

  const int nsteps = Kpad / 32;

  float4 vA0, vA1, nA0, nA1;
  nA0 = nA1 = make_float4(0.f, 0.f, 0.f, 0.f);

  auto stageB = [&](int s, int nb) {
    const int k0 = s * 32;
    async_ld16(&Bls[nb][0][(w * 16) * 32], Bth + boff0 + k0);
    async_ld16(&Bls[nb][0][(64 + w * 16) * 32], Bth + boff1 + k0);
    async_ld16(&Bls[nb][1][(w * 16) * 32], Btl + boff0 + k0);
    async_ld16(&Bls[nb][1][(64 + w * 16) * 32], Btl + boff1 + k0);
  };
  auto loadA = [&](int s, float4& x0, float4& x1) {
    const int k0 = s * 32 + q * 8;
    x0 = make_float4(0.f, 0.f, 0.f, 0.f);
    x1 = x0;
    if (rok) {
      if (k0 + 4 <= K) x0 = *(const float4*)&A[abase + k0];
      if (k0 + 8 <= K) x1 = *(const float4*)&A[abase + k0 + 4];
    }
  };

  stageB(0, 0);
  loadA(0, vA0, vA1);
  __syncthreads();

  for (int s = 0; s < nsteps; s++) {
    const int cur = s & 1;
    if (s + 1 < nsteps) {
      stageB(s + 1, 1 ^ cur);
      loadA(s + 1, nA0, nA1);
    }
    float av[8] = {vA0.x, vA0.y, vA0.z, vA0.w, vA1.x, vA1.y, vA1.z, vA1.w};
    union {
      unsigned u[4];
      short8 s8;
    } Uh, Ul;
#pragma unroll
    for (int i = 0; i < 4; i++) {
      unsigned short ha, la, hb, lb;
      split_bf16(av[2 * i], ha, la);
      split_bf16(av[2 * i + 1], hb, lb);
      Uh.u[i] = (unsigned)ha | ((unsigned)hb << 16);
      Ul.u[i] = (unsigned)la | ((unsigned)lb << 16);
    }
    short8 afh = Uh.s8, afl = Ul.s8;
#pragma unroll
    for (int ct = 0; ct < 8; ct++) {
      int n = ct * 16 + m16;
      int qv = (q ^ ((n >> 1) & 3)) * 8;
      short8 bfh = *(const short8*)&Bls[cur][0][n * 32 + qv];
      short8 bfl = *(const short8*)&Bls[cur][1][n * 32 + qv];
      acc[ct] = __builtin_amdgcn_mfma_f32_16x16x32_bf16(afh, bfh, acc[ct], 0, 0, 0);
      acc[ct] = __builtin_amdgcn_mfma_f32_16x16x32_bf16(afh, bfl, acc[ct], 0, 0, 0);
      acc[ct] = __builtin_amdgcn_mfma_f32_16x16x32_bf16(afl, bfh, acc[ct], 0, 0, 0);
    }
    vA0 = nA0;
    vA1 = nA1;
    __syncthreads();
  }

  float avs_r[8], avd_r[8];
#pragma unroll
  for (int ct = 0; ct < 8; ct++) {
    avs_r[ct] = avs[ct * 16 + m16];
    avd_r[ct] = avd[ct * 16 + m16];
  }
#pragma unroll
  for (int reg = 0; reg < 4; reg++) {
    int grow = row0 + w * 16 + q * 4 + reg;
    bool ok = grow < M;
    float ps = 0.f, pd = 0.f;
#pragma unroll
    for (int ct = 0; ct < 8; ct++) {
      float c = acc[ct][reg];
      if (ok) C[(long)grow * 128 + ct * 16 + m16] = f2bf_rne(c);
      ps = fmaf(c, avs_r[ct], ps);
      pd = fmaf(c, avd_r[ct], pd);
    }
#pragma unroll
    for (int d = 1; d < 16; d <<= 1) {
      ps += __shfl_xor(ps, d, 64);
      pd += __shfl_xor(pd, d, 64);
    }
    if (m16 == 0 && ok) {
      aS[grow] = ps;
      aD[grow] = pd;
    }
  }
}

// ---------------- softmax attention + aggregation: HALF-WAVE per dst ----------------
// 2 dsts per wave (NN % 8 == 0 -> exact grid fit): softmax/reduce/gelu
// instruction cost per dst halves. Within a half: 2 edge-slots x 16 lanes x
// uint4 (256B row), unroll 2 => 4 edges in flight. Rare deg>32 (Poisson(17)
// tail): wave-uniform ballot -> full-wave fallback run twice sequentially.

__global__ __launch_bounds__(256) void aggregate_kernel(const int* __restrict__ rowptr,
                                                        const int* __restrict__ colA,
                                                        const float* __restrict__ aS,
                                                        const float* __restrict__ aD,
                                                        const unsigned short* __restrict__ Hb,
                                                        const float* __restrict__ bias,
                                                        float* __restrict__ out,
                                                        int apply_gelu) {
  const int lane = threadIdx.x & 63;
  const int w = threadIdx.x >> 6;
  const int pair = blockIdx.x * 8 + w * 2;
  const int half = lane >> 5;
  const int hl = lane & 31;
  const int dst = pair + half;  // always < NN (NN divisible by 8)
  const int start = rowptr[dst];
  const int end = rowptr[dst + 1];
  const int deg = end - start;

  unsigned long long bal = __ballot(deg <= 32);
  if (bal == ~0ull) {
    // ---- paired fast path: this half-wave handles dst
    const float ad = aD[dst];
    int src = 0;
    float e = -__builtin_inff();
    if (hl < deg) {
      src = colA[start + hl];
      float v = aS[src] + ad;
      e = (v > 0.f) ? v : 0.2f * v;
    }
    float mx = e;
#pragma unroll
    for (int d = 1; d < 32; d <<= 1) mx = fmaxf(mx, __shfl_xor(mx, d, 32));
    float ew = (hl < deg) ? expf(e - mx) : 0.f;
    float ss = ew;
#pragma unroll
    for (int d = 1; d < 32; d <<= 1) ss += __shfl_xor(ss, d, 32);
    float wgt = ew * (1.f / ss);

    const int qg2 = hl >> 4;   // edge slot within half
    const int fl = hl & 15;    // feature octet
    const int base = half * 32;

    float a0 = 0.f, a1 = 0.f, a2 = 0.f, a3 = 0.f;
    float a4 = 0.f, a5 = 0.f, a6 = 0.f, a7 = 0.f;
    for (int j = 0; j < deg; j += 4) {
      int i0 = j + qg2;
      int i1 = j + 2 + qg2;
      int sj0 = __shfl(src, base + (i0 & 31), 64);
      float wj0 = __shfl(wgt, base + (i0 & 31), 64);
      if (i0 >= deg) wj0 = 0.f;
      int sj1 = __shfl(src, base + (i1 & 31), 64);
      float wj1 = __shfl(wgt, base + (i1 & 31), 64);
      if (i1 >= deg) wj1 = 0.f;
      uint4 u0 = *(const uint4*)&Hb[(long)sj0 * DH + fl * 8];
      uint4 u1 = *(const uint4*)&Hb[(long)sj1 * DH + fl * 8];
      a0 = fmaf(wj0, bf_lo(u0.x), a0);
      a1 = fmaf(wj0, bf_hi(u0.x), a1);
      a2 = fmaf(wj0, bf_lo(u0.y), a2);
      a3 = fmaf(wj0, bf_hi(u0.y), a3);
      a4 = fmaf(wj0, bf_lo(u0.z), a4);
      a5 = fmaf(wj0, bf_hi(u0.z), a5);
      a6 = fmaf(wj0, bf_lo(u0.w), a6);
      a7 = fmaf(wj0, bf_hi(u0.w), a7);
      a0 = fmaf(wj1, bf_lo(u1.x), a0);
      a1 = fmaf(wj1, bf_hi(u1.x), a1);
      a2 = fmaf(wj1, bf_lo(u1.y), a2);
      a3 = fmaf(wj1, bf_hi(u1.y), a3);
      a4 = fmaf(wj1, bf_lo(u1.z), a4);
      a5 = fmaf(wj1, bf_hi(u1.z), a5);
      a6 = fmaf(wj1, bf_lo(u1.w), a6);
      a7 = fmaf(wj1, bf_hi(u1.w), a7);
    }
    // combine the two edge-slot partials (xor 16 stays within the 32-half)
    a0 += __shfl_xor(a0, 16, 64);
    a1 += __shfl_xor(a1, 16, 64);
    a2 += __shfl_xor(a2, 16, 64);
    a3 += __shfl_xor(a3, 16, 64);
    a4 += __shfl_xor(a4, 16, 64);
    a5 += __shfl_xor(a5, 16, 64);
    a6 += __shfl_xor(a6, 16, 64);
    a7 += __shfl_xor(a7, 16, 64);

    if (qg2 == 0) {
      float4 b0 = *(const float4*)&bias[fl * 8];
      float4 b1 = *(const float4*)&bias[fl * 8 + 4];
      float r0 = a0 + b0.x, r1 = a1 + b0.y, r2 = a2 + b0.z, r3 = a3 + b0.w;
      float r4 = a4 + b1.x, r5 = a5 + b1.y, r6 = a6 + b1.z, r7 = a7 + b1.w;
      if (apply_gelu) {
        r0 = gelu_exact(r0); r1 = gelu_exact(r1);
        r2 = gelu_exact(r2); r3 = gelu_exact(r3);
        r4 = gelu_exact(r4); r5 = gelu_exact(r5);
        r6 = gelu_exact(r6); r7 = gelu_exact(r7);
      }
      *(float4*)&out[(long)dst * DH + fl * 8] = make_float4(r0, r1, r2, r3);
      *(float4*)&out[(long)dst * DH + fl * 8 + 4] = make_float4(r4, r5, r6, r7);
    }
    return;
  }

  // ---- slow path (rare): full wave processes each dst of the pair in turn
  const int qg = lane >> 4;
  const int fl = lane & 15;
  for (int t = 0; t < 2; t++) {
    const int d2 = pair + t;
    const int st = rowptr[d2];
    const int en = rowptr[d2 + 1];
    const int dg = en - st;
    const float ad = aD[d2];

    float a0 = 0.f, a1 = 0.f, a2 = 0.f, a3 = 0.f;
    float a4 = 0.f, a5 = 0.f, a6 = 0.f, a7 = 0.f;

    auto gather8 = [&](int sj0, float wj0, int sj1, float wj1) {
      uint4 u0 = *(const uint4*)&Hb[(long)sj0 * DH + fl * 8];
      uint4 u1 = *(const uint4*)&Hb[(long)sj1 * DH + fl * 8];
      a0 = fmaf(wj0, bf_lo(u0.x), a0);
      a1 = fmaf(wj0, bf_hi(u0.x), a1);
      a2 = fmaf(wj0, bf_lo(u0.y), a2);
      a3 = fmaf(wj0, bf_hi(u0.y), a3);
      a4 = fmaf(wj0, bf_lo(u0.z), a4);
      a5 = fmaf(wj0, bf_hi(u0.z), a5);
      a6 = fmaf(wj0, bf_lo(u0.w), a6);
      a7 = fmaf(wj0, bf_hi(u0.w), a7);
      a0 = fmaf(wj1, bf_lo(u1.x), a0);
      a1 = fmaf(wj1, bf_hi(u1.x), a1);
      a2 = fmaf(wj1, bf_lo(u1.y), a2);
      a3 = fmaf(wj1, bf_hi(u1.y), a3);
      a4 = fmaf(wj1, bf_lo(u1.z), a4);
      a5 = fmaf(wj1, bf_hi(u1.z), a5);
      a6 = fmaf(wj1, bf_lo(u1.w), a6);
      a7 = fmaf(wj1, bf_hi(u1.w), a7);
    };

    if (dg <= 64) {
      int src = 0;
      float e = -__builtin_inff();
      if (lane < dg) {
        src = colA[st + lane];
        float v = aS[src] + ad;
        e = (v > 0.f) ? v : 0.2f * v;
      }
      float mx = e;
#pragma unroll
      for (int d = 1; d < 64; d <<= 1) mx = fmaxf(mx, __shfl_xor(mx, d, 64));
      float ew = (lane < dg) ? expf(e - mx) : 0.f;
      float ss = ew;
#pragma unroll
      for (int d = 1; d < 64; d <<= 1) ss += __shfl_xor(ss, d, 64);
      float wgt = ew * (1.f / ss);
      for (int j = 0; j < dg; j += 8) {
        int i0 = j + qg;
        int i1 = j + 4 + qg;
        int sj0 = __shfl(src, i0 & 63, 64);
        float wj0 = __shfl(wgt, i0 & 63, 64);
        if (i0 >= dg) wj0 = 0.f;
        int sj1 = __shfl(src, i1 & 63, 64);
        float wj1 = __shfl(wgt, i1 & 63, 64);
        if (i1 >= dg) wj1 = 0.f;
        gather8(sj0, wj0, sj1, wj1);
      }
    } else {
      float m = -__builtin_inff(), ssum = 0.f;
      for (int c0 = st; c0 < en; c0 += 64) {
        int i = c0 + lane;
        float e = -__builtin_inff();
        if (i < en) {
          int s = colA[i];
          float v = aS[s] + ad;
          e = (v > 0.f) ? v : 0.2f * v;
        }
        float cm = e;
#pragma unroll
        for (int d = 1; d < 64; d <<= 1) cm = fmaxf(cm, __shfl_xor(cm, d, 64));
        float ce = (i < en) ? expf(e - cm) : 0.f;
        float cs = ce;
#pragma unroll
        for (int d = 1; d < 64; d <<= 1) cs += __shfl_xor(cs, d, 64);
        float nm = fmaxf(m, cm);
        ssum = ssum * expf(m - nm) + cs * expf(cm - nm);
        m = nm;
      }
      float inv = 1.f / ssum;
      for (int c0 = st; c0 < en; c0 += 64) {
        int i = c0 + lane;
        int src = 0;
        float wgt = 0.f;
        if (i < en) {
          src = colA[i];
          float v = aS[src] + ad;
          float e = (v > 0.f) ? v : 0.2f * v;
          wgt = expf(e - m) * inv;
        }
        int lim = min(64, en - c0);
        for (int j = 0; j < lim; j += 8) {
          int i0 = j + qg;
          int i1 = j + 4 + qg;
          int sj0 = __shfl(src, i0 & 63, 64);
          float wj0 = __shfl(wgt, i0 & 63, 64);
          if (i0 >= lim) wj0 = 0.f;
          int sj1 = __shfl(src, i1 & 63, 64);
          float wj1 = __shfl(wgt, i1 & 63, 64);
          if (i1 >= lim) wj1 = 0.f;
          gather8(sj0, wj0, sj1, wj1);
        }
      }
    }

#pragma unroll
    for (int d = 16; d <= 32; d <<= 1) {
      a0 += __shfl_xor(a0, d, 64);
      a1 += __shfl_xor(a1, d, 64);
      a2 += __shfl_xor(a2, d, 64);
      a3 += __shfl_xor(a3, d, 64);
      a4 += __shfl_xor(a4, d, 64);
      a5 += __shfl_xor(a5, d, 64);
      a6 += __shfl_xor(a6, d, 64);
      a7 += __shfl_xor(a7, d, 64);
    }

    if (qg == 0) {
      float4 b0 = *(const float4*)&bias[fl * 8];
      float4 b1 = *(const float4*)&bias[fl * 8 + 4];
      float r0 = a0 + b0.x, r1 = a1 + b0.y, r2 = a2 + b0.z, r3 = a3 + b0.w;
      float r4 = a4 + b1.x, r5 = a5 + b1.y, r6 = a6 + b1.z, r7 = a7 + b1.w;
      if (apply_gelu) {
        r0 = gelu_exact(r0); r1 = gelu_exact(r1);
        r2 = gelu_exact(r2); r3 = gelu_exact(r3);
        r4 = gelu_exact(r4); r5 = gelu_exact(r5);
        r6 = gelu_exact(r6); r7 = gelu_exact(r7);
      }
      *(float4*)&out[(long)d2 * DH + fl * 8] = make_float4(r0, r1, r2, r3);
      *(float4*)&out[(long)d2 * DH + fl * 8 + 4] = make_float4(r4, r5, r6, r7);
    }
  }
}

// ---------------- masked per-graph mean pooling (batch is sorted) ----------------

__global__ __launch_bounds__(128) void pool_kernel(const float* __restrict__ H,
                                                   const int* __restrict__ batch,
                                                   const int* __restrict__ pos,
                                                   float* __restrict__ sums,
                                                   float* __restrict__ cnt) {
  const int CH = 64;
  int n0 = blockIdx.x * CH;
  int n1 = min(n0 + CH, NN);
  int f = threadIdx.x;
  float acc = 0.f, c = 0.f;
  int g = batch[n0];
  for (int n = n0; n < n1; n += 4) {
    float h0 = H[(long)(n + 0) * DH + f];
    float h1 = H[(long)(n + 1) * DH + f];
    float h2 = H[(long)(n + 2) * DH + f];
    float h3 = H[(long)(n + 3) * DH + f];
    int g0 = batch[n + 0], g1 = batch[n + 1], g2 = batch[n + 2], g3 = batch[n + 3];
    int p0 = pos[n + 0], p1 = pos[n + 1], p2 = pos[n + 2], p3 = pos[n + 3];
    float hv[4] = {h0, h1, h2, h3};
    int gv[4] = {g0, g1, g2, g3};
    int pv[4] = {p0, p1, p2, p3};
#pragma unroll
    for (int i = 0; i < 4; i++) {
      if (gv[i] != g) {
        atomicAdd(&sums[g * DH + f], acc);
        if (f == 0) atomicAdd(&cnt[g], c);
        acc = 0.f; c = 0.f; g = gv[i];
      }
      if (pv[i]) {
        acc += hv[i];
        c += 1.f;
      }
    }
  }
  atomicAdd(&sums[g * DH + f], acc);
  if (f == 0) atomicAdd(&cnt[g], c);
}

// ---------------- head ----------------

__global__ __launch_bounds__(128) void head_kernel(const float* __restrict__ sums,
                                                   const float* __restrict__ cnt,
                                                   const float* __restrict__ Wfc,
                                                   const float* __restrict__ bfc,
                                                   float* __restrict__ out) {
  int g = blockIdx.x;
  int f = threadIdx.x;
  float c = fmaxf(cnt[g], 1.f);
  float logit = sums[g * DH + f] / c;
  out[NG + g * DH + f] = logit;
  float gl = gelu_exact(logit) * Wfc[f];
  __shared__ float red[2];
#pragma unroll
  for (int d = 1; d < 64; d <<= 1) gl += __shfl_xor(gl, d, 64);
  int lane = f & 63, w = f >> 6;
  if (lane == 0) red[w] = gl;
  __syncthreads();
  if (f == 0) out[g] = red[0] + red[1] + bfc[0];
}

// ---------------- launch ----------------

extern "C" void kernel_launch(void* const* d_in, const int* in_sizes, int n_in,
                              void* d_out, int out_size, void* d_ws, size_t ws_size,
                              hipStream_t stream) {
  const float* x   = (const float*)d_in[0];
  const int* ei    = (const int*)d_in[1];
  const int* batch = (const int*)d_in[2];
  const int* pos   = (const int*)d_in[3];
  const float* W1  = (const float*)d_in[5];
  const float* as1 = (const float*)d_in[6];
  const float* ad1 = (const float*)d_in[7];
  const float* b1  = (const float*)d_in[8];
  const float* W2  = (const float*)d_in[9];
  const float* as2 = (const float*)d_in[10];
  const float* ad2 = (const float*)d_in[11];
  const float* b2  = (const float*)d_in[12];
  const float* Wfc = (const float*)d_in[13];
  const float* bfc = (const float*)d_in[14];
  float* out = (float*)d_out;

  const int KP1 = 320;
  const int KP2 = 128;
  const int NB_SCAN = (NN + 1023) / 1024;  // 49
  const int BPR = 416;                      // blocks per dst-range (x8 ranges)

  char* ws = (char*)d_ws;
  size_t off = 0;
  auto nxt = [&](size_t b) -> void* {
    size_t p = off;
    off += (b + 255) & ~(size_t)255;
    return (void*)(ws + p);
  };
  int* rowptr = (int*)nxt((NN + 1) * sizeof(int));
  int* cursor = (int*)nxt(NN * sizeof(int));
  int* colA   = (int*)nxt((size_t)(EE + NN) * sizeof(int));
  int* bsum   = (int*)nxt((NB_SCAN + 1) * sizeof(int));
  float* aS   = (float*)nxt((size_t)2 * NN * sizeof(float));
  float* aD   = aS + NN;
  unsigned short* bufAb = (unsigned short*)nxt((size_t)NN * DH * sizeof(short));
  float* bufB = (float*)nxt((size_t)NN * DH * sizeof(float));
  float* sums = (float*)nxt((size_t)(NG * DH + NG) * sizeof(float));
  float* cnt  = sums + NG * DH;
  unsigned short* Bt1h = (unsigned short*)nxt((size_t)128 * KP1 * sizeof(short));
  unsigned short* Bt1l = (unsigned short*)nxt((size_t)128 * KP1 * sizeof(short));
  unsigned short* Bt2h = (unsigned short*)nxt((size_t)128 * KP2 * sizeof(short));
  unsigned short* Bt2l = (unsigned short*)nxt((size_t)128 * KP2 * sizeof(short));

  hipMemsetAsync(cursor, 0, NN * sizeof(int), stream);
  hipMemsetAsync(sums, 0, (NG * DH + NG) * sizeof(float), stream);

  const int cb1 = (128 * KP1 + 255) / 256;
  const int cb2 = (128 * KP2 + 255) / 256;
  convert_bt2_kernel<<<cb1 + cb2, 256, 0, stream>>>(W1, Bt1h, Bt1l, DIN, KP1, cb1,
                                                    W2, Bt2h, Bt2l, DH, KP2);

  count_part_kernel<<<8 * BPR, 256, 0, stream>>>(ei, cursor, BPR);
  scan_part_kernel<<<NB_SCAN, 1024, 0, stream>>>(cursor, rowptr, bsum);
  scan_add_kernel<<<(NN + 1 + 255) / 256, 256, 0, stream>>>(rowptr, bsum, cursor, NB_SCAN);
  scatter_part_kernel<<<8 * BPR, 256, 0, stream>>>(ei, cursor, colA, BPR);

  const int gblocks = (NN + 63) / 64;
  // layer 1
  gemm_mfma_kernel<<<gblocks, 256, 0, stream>>>(x, Bt1h, Bt1l, bufAb, NN, DIN, KP1,
                                                as1, ad1, aS, aD);
  aggregate_kernel<<<NN / 8, 256, 0, stream>>>(rowptr, colA, aS, aD, bufAb, b1, bufB, 1);
  // layer 2
  gemm_mfma_kernel<<<gblocks, 256, 0, stream>>>(bufB, Bt2h, Bt2l, bufAb, NN, DH, KP2,
                                                as2, ad2, aS, aD);
  aggregate_kernel<<<NN / 8, 256, 0, stream>>>(rowptr, colA, aS, aD, bufAb, b2, bufB, 0);
  // pooling + head
  pool_kernel<<<(NN + 63) / 64, 128, 0, stream>>>(bufB, batch, pos, sums, cnt);
  head_kernel<<<NG, 128, 0, stream>>>(sums, cnt, Wfc, bfc, out);
}